// Round 8
// baseline (761.103 us; speedup 1.0000x reference)
//
#include <hip/hip_runtime.h>
#include <hip/hip_bf16.h>
#include <cstdint>
#include <cstddef>

#define B_ 2048
#define H_ 1024
#define S_ 32768
#define D_ 64
#define BT 32
#define KQ 1024   // GEMM K (query only); cl & bias folded into fp32 epilogue
#define KQS 1056  // stored row stride in u16 (2112B, non-power-of-2)
#define NT 16     // K-tiles of 64

typedef unsigned char u8;
typedef unsigned short u16;
typedef __attribute__((ext_vector_type(8))) short bf16x8;
typedef __attribute__((ext_vector_type(8))) unsigned short ushort8v;
typedef __attribute__((ext_vector_type(4))) float f32x4;

// workspace layout (float offsets) -- shared by fast + fallback paths
#define WS_CMEAN      0
#define WS_PCMEAN     64
#define WS_CMM        128                    // content mean [H]
#define WS_ZR         (WS_CMM + H_)          // [B]
#define WS_TR         (WS_ZR + B_)           // [B]
#define WS_VR         (WS_TR + B_)           // [B*D]
#define WS_ZW         (WS_VR + B_*D_)        // [B]
#define WS_WWM        (WS_ZW + B_)           // [S]
#define WS_END        (WS_WWM + S_)          // 171136 floats

__device__ __forceinline__ u16 f2bf(float f) {
  unsigned u = __float_as_uint(f);
  unsigned r = (u + 0x7FFFu + ((u >> 16) & 1u)) >> 16;
  return (u16)r;
}

__device__ __forceinline__ float bf2f(u16 v) {
  return __uint_as_float(((unsigned)v) << 16);
}

// fp8 e4m3fn encode (f > 0, clamped to 448), RNE
__device__ __forceinline__ u8 f8enc(float f) {
  f = fminf(f, 448.f);
  unsigned u = __float_as_uint(f);
  int ex = (int)((u >> 23) & 255) - 127;
  unsigned r;
  if (ex >= -6) {
    unsigned m = u & 0x7FFFFF;
    unsigned rm = (m + 0x7FFFF + ((m >> 20) & 1)) >> 20;
    r = ((unsigned)(ex + 7) << 3) + rm;
  } else {
    r = (unsigned)fminf(7.f, f * 512.f + 0.5f);
  }
  return (u8)(r > 126 ? 126 : r);
}

__device__ __forceinline__ float f8dec(u8 b) {
  int ef = (b >> 3) & 15, m = b & 7;
  return ef ? __uint_as_float(((unsigned)(ef + 120) << 23) | ((unsigned)m << 20))
            : (float)m * 0.001953125f;
}

__device__ __forceinline__ void gload_lds16(const void* g, void* l) {
  __builtin_amdgcn_global_load_lds(
      (const __attribute__((address_space(1))) unsigned int*)g,
      (__attribute__((address_space(3))) unsigned int*)l, 16, 0, 0);
}

// ================= FAST PATH =================

// merged preprocessing: stats + cvt_q + cvt_memT + cvt_wt(read)
// grid sections (256 thr): [0,128) content-mean, [128,160) cl-mean,
// [160,2208) qb cast, [2208,2720) memT, [2720,10912) wbtR
__global__ void k_pre(const float* __restrict__ query, const float* __restrict__ cl,
                      const float* __restrict__ content, const float* __restrict__ mem,
                      const float* __restrict__ Wr,
                      u16* __restrict__ qb, u16* __restrict__ mT,
                      u16* __restrict__ wbtR, float* __restrict__ ws) {
  const int blk = blockIdx.x, t = threadIdx.x;
  if (blk < 128) {
    const int h = (blk & 3) * 256 + t;
    const int b0 = (blk >> 2) * 64;
    float acc = 0.f;
    #pragma unroll 8
    for (int b = 0; b < 64; ++b) acc += content[(size_t)(b0 + b) * H_ + h];
    atomicAdd(&ws[WS_CMM + h], acc * (1.0f / B_));
  } else if (blk < 160) {
    if (t < 64) {
      float acc = cl[(blk - 128) * 64 + t];
      #pragma unroll
      for (int off = 32; off > 0; off >>= 1) acc += __shfl_down(acc, off);
      if (t == 0) atomicAdd(&ws[WS_CMEAN], acc * (1.0f / B_));
    }
  } else if (blk < 160 + B_) {
    const int b = blk - 160;
    const float4 q4 = *reinterpret_cast<const float4*>(&query[(size_t)b * H_ + t * 4]);
    ushort4 o;
    o.x = f2bf(q4.x); o.y = f2bf(q4.y); o.z = f2bf(q4.z); o.w = f2bf(q4.w);
    *reinterpret_cast<ushort4*>(&qb[(size_t)b * KQS + t * 4]) = o;
  } else if (blk < 160 + B_ + 512) {
    __shared__ float tile[64][65];
    const int s0 = (blk - 160 - B_) * 64;
    const int c = t & 63, rbase = t >> 6;
    #pragma unroll
    for (int i = 0; i < 16; ++i) {
      const int r = rbase + i * 4;
      tile[r][c] = mem[(size_t)(s0 + r) * D_ + c];
    }
    __syncthreads();
    #pragma unroll
    for (int i = 0; i < 16; ++i) {
      const int d = rbase + i * 4;
      mT[(size_t)d * S_ + s0 + c] = f2bf(tile[c][d]);
    }
  } else {
    const int i = blk - (160 + B_ + 512);
    __shared__ float tile[64][65];
    const int s0 = (i & 511) * 64;
    const int k0 = (i >> 9) * 64;
    const int c = t & 63, rbase = t >> 6;
    #pragma unroll
    for (int j = 0; j < 16; ++j) {
      const int r = rbase + j * 4;
      tile[r][c] = Wr[(size_t)(k0 + r) * S_ + s0 + c];
    }
    __syncthreads();
    #pragma unroll
    for (int j = 0; j < 16; ++j) {
      const int sr = rbase + j * 4;
      wbtR[(size_t)(s0 + sr) * KQS + k0 + c] = f2bf(tile[c][sr]);
    }
  }
}

// W [1025][S] fp32 -> wbt [S][KQS] bf16 transposed (first 1024 rows only)
__global__ void k_cvt_wtW(const float* __restrict__ W, u16* __restrict__ wbt) {
  __shared__ float tile[64][65];
  const int t = threadIdx.x;
  const int s0 = blockIdx.x * 64;
  const int k0 = blockIdx.y * 64;
  const int c = t & 63, rbase = t >> 6;
  #pragma unroll
  for (int j = 0; j < 16; ++j) {
    const int r = rbase + j * 4;
    tile[r][c] = W[(size_t)(k0 + r) * S_ + s0 + c];
  }
  __syncthreads();
  #pragma unroll
  for (int j = 0; j < 16; ++j) {
    const int sr = rbase + j * 4;
    wbt[(size_t)(s0 + sr) * KQS + k0 + c] = f2bf(tile[c][sr]);
  }
}

// LDS frag read: 16x16x32 A/B operand, rows rowbase+f*16+lr, 8-slot XOR swizzle
template <int NF>
__device__ __forceinline__ void rd_frags(const u16* __restrict__ lds, int rowbase,
                                         int lr, int lg, bf16x8 (&dst)[NF * 2]) {
  #pragma unroll
  for (int f = 0; f < NF; ++f) {
    const int rr = rowbase + f * 16 + lr;
    #pragma unroll
    for (int ks = 0; ks < 2; ++ks) {
      const int ch = (ks * 4 + lg) ^ (rr & 7);
      dst[f * 2 + ks] = *(const bf16x8*)&lds[rr * 64 + ch * 8];
    }
  }
}

template <int QR, int QC>
__device__ __forceinline__ void mfmaq(f32x4 (&acc)[8][4], const bf16x8 (&av)[8],
                                      const bf16x8 (&bv)[4]) {
  #pragma unroll
  for (int m16 = 0; m16 < 4; ++m16)
    #pragma unroll
    for (int n16 = 0; n16 < 2; ++n16)
      #pragma unroll
      for (int ks = 0; ks < 2; ++ks)
        acc[QR * 4 + m16][QC * 2 + n16] = __builtin_amdgcn_mfma_f32_16x16x32_bf16(
            av[m16 * 2 + ks], bv[n16 * 2 + ks], acc[QR * 4 + m16][QC * 2 + n16], 0, 0, 0);
}

// Fused bf16 MFMA GEMM, 8-phase/counted-vmcnt schedule, K=1024 (NT=16),
// stored stride KQS=1056 u16 (non-power-of-2).
// logit = (qb @ wbt^T)[r][c] + cl[r]*W[1024][c] + bias[c] (fp32 epilogue add).
//  VARIANT 0 (read): P=e*strength -> pout bf16 (scatter), Z/T row atomics.
//  VARIANT 1 (write): e -> LDS, coalesced fp8 e4m3 readout -> pout, Zw atomics.
// Block 512 thr (8 waves 2Mx4N), tile 256x256, BK=64, LDS 128KB.
template <int VARIANT>
__global__ __launch_bounds__(512, 2) void k_gemm(
    const u16* __restrict__ qb, const u16* __restrict__ wbt,
    const float* __restrict__ Wfull, const float* __restrict__ biasv,
    const float* __restrict__ cl, const float* __restrict__ strength,
    void* __restrict__ pout, float* __restrict__ ws) {
  __shared__ __align__(16) u16 SMEM[4][256 * 64];  // [0..1]=A dbuf, [2..3]=B dbuf
  const int t = threadIdx.x;
  const int w = t >> 6, l = t & 63;
  const int wm = w >> 2, wn = w & 3;          // 2 x 4 waves
  const int lr = l & 15, lg = l >> 4;

  // bijective XCD-chunked remap: each XCD owns 16 contiguous col-blocks
  const int lin = blockIdx.x + 8 * blockIdx.y;   // gridDim = (8, 128)
  const int xcd = lin & 7, idx = lin >> 3;
  const size_t r0 = (size_t)(idx & 7) * 256;
  const int cblk = xcd * 16 + (idx >> 3);
  const size_t c0 = (size_t)cblk * 256;

  f32x4 acc[8][4];
  #pragma unroll
  for (int m = 0; m < 8; ++m)
    #pragma unroll
    for (int n = 0; n < 4; ++n) acc[m][n] = (f32x4)0.f;

  // stage K-tile kt2 into buffer pp: 8 gloads/thread, source pre-swizzled
  auto STAGE = [&](int kt2, int pp) {
    #pragma unroll
    for (int i = 0; i < 4; ++i) {
      const int q = i * 512 + t;
      const int r = q >> 3;
      const int sc = (q & 7) ^ (r & 7);
      gload_lds16(qb + (r0 + r) * KQS + (size_t)kt2 * 64 + sc * 8, &SMEM[pp][q * 8]);
    }
    #pragma unroll
    for (int i = 0; i < 4; ++i) {
      const int q = i * 512 + t;
      const int r = q >> 3;
      const int sc = (q & 7) ^ (r & 7);
      gload_lds16(wbt + (c0 + r) * KQS + (size_t)kt2 * 64 + sc * 8, &SMEM[2 + pp][q * 8]);
    }
  };

  // prologue: 2 K-tiles in flight
  STAGE(0, 0);
  STAGE(1, 1);
  asm volatile("s_waitcnt vmcnt(8)" ::: "memory");   // kt0 arrived, kt1 flying
  __builtin_amdgcn_sched_barrier(0);
  __builtin_amdgcn_s_barrier();

  for (int kt = 0; kt < NT; ++kt) {
    const int p = kt & 1;
    const u16* __restrict__ Ap = &SMEM[p][0];
    const u16* __restrict__ Bp = &SMEM[2 + p][0];
    bf16x8 a[8], b0[4], b1[4];
    // phase 1: read A(qr0)+B(qc0); MFMA quadrant (0,0)
    rd_frags<4>(Ap, wm * 128 + 0, lr, lg, a);
    rd_frags<2>(Bp, wn * 64 + 0, lr, lg, b0);
    __builtin_amdgcn_sched_barrier(0);
    __builtin_amdgcn_s_barrier();
    __builtin_amdgcn_s_setprio(1);
    mfmaq<0, 0>(acc, a, b0);
    __builtin_amdgcn_s_setprio(0);
    __builtin_amdgcn_s_barrier();
    // phase 2: read B(qc1); MFMA (0,1)
    rd_frags<2>(Bp, wn * 64 + 32, lr, lg, b1);
    __builtin_amdgcn_sched_barrier(0);
    __builtin_amdgcn_s_barrier();
    __builtin_amdgcn_s_setprio(1);
    mfmaq<0, 1>(acc, a, b1);
    __builtin_amdgcn_s_setprio(0);
    __builtin_amdgcn_s_barrier();
    // phase 3: read A(qr1); MFMA (1,1)
    rd_frags<4>(Ap, wm * 128 + 64, lr, lg, a);
    __builtin_amdgcn_sched_barrier(0);
    __builtin_amdgcn_s_barrier();
    __builtin_amdgcn_s_setprio(1);
    mfmaq<1, 1>(acc, a, b1);
    __builtin_amdgcn_s_setprio(0);
    __builtin_amdgcn_s_barrier();
    // phase 4: buf[p] LDS fully consumed -> stage kt+2 into it; MFMA (1,0) from regs
    if (kt + 2 < NT) STAGE(kt + 2, p);
    __builtin_amdgcn_s_barrier();
    __builtin_amdgcn_s_setprio(1);
    mfmaq<1, 0>(acc, a, b0);
    __builtin_amdgcn_s_setprio(0);
    if (kt + 2 < NT) {
      asm volatile("s_waitcnt vmcnt(8)" ::: "memory");   // kt+1 arrived, kt+2 flying
    } else if (kt + 1 < NT) {
      asm volatile("s_waitcnt vmcnt(0)" ::: "memory");   // tail drain
    }
    __builtin_amdgcn_sched_barrier(0);
    __builtin_amdgcn_s_barrier();
  }

  // ---------- epilogue ----------
  // C/D layout: col=lane&15, row=(lane>>4)*4+reg
  // fp32 rank-1 adjust: logit += cl[row]*W[1024][col] + bias[col]
  float wl4[4], bb4[4];
  #pragma unroll
  for (int n = 0; n < 4; ++n) {
    const size_t col = c0 + wn * 64 + n * 16 + lr;
    wl4[n] = Wfull[(size_t)H_ * S_ + col];
    bb4[n] = biasv[col];
  }
  #pragma unroll
  for (int m = 0; m < 8; ++m) {
    #pragma unroll
    for (int j = 0; j < 4; ++j) {
      const float clv = cl[r0 + wm * 128 + m * 16 + lg * 4 + j];
      #pragma unroll
      for (int n = 0; n < 4; ++n)
        acc[m][n][j] += fmaf(clv, wl4[n], bb4[n]);
    }
  }

  if (VARIANT == 0) {
    // round-3-style scatter epilogue: P bf16 + Z/T LDS reduce + atomics
    float* zred = (float*)&SMEM[0][0];     // [256]
    float* tred = zred + 256;              // [256]
    if (t < 512) zred[t] = 0.f;            // covers both arrays
    __syncthreads();
    u16* __restrict__ pout16 = (u16*)pout;
    float st4[4];
    #pragma unroll
    for (int n = 0; n < 4; ++n) st4[n] = strength[c0 + wn * 64 + n * 16 + lr];
    #pragma unroll
    for (int m = 0; m < 8; ++m) {
      #pragma unroll
      for (int j = 0; j < 4; ++j) {
        const int rloc = wm * 128 + m * 16 + lg * 4 + j;
        const size_t R = r0 + rloc;
        float ze = 0.f, zp = 0.f;
        u16 pb[4];
        #pragma unroll
        for (int n = 0; n < 4; ++n) {
          const float e = __expf(acc[m][n][j]);
          const float pq = e * st4[n];
          ze += e;
          zp += pq;
          pb[n] = f2bf(pq);
        }
        #pragma unroll
        for (int n = 0; n < 4; ++n)
          pout16[R * S_ + c0 + wn * 64 + n * 16 + lr] = pb[n];
        #pragma unroll
        for (int off = 1; off < 16; off <<= 1) {
          ze += __shfl_xor(ze, off);
          zp += __shfl_xor(zp, off);
        }
        if (lr == 0) {
          atomicAdd(&zred[rloc], ze);
          atomicAdd(&tred[rloc], zp);
        }
      }
    }
    __syncthreads();
    if (t < 256) {
      atomicAdd(&ws[WS_ZR + r0 + t], zred[t]);
      atomicAdd(&ws[WS_TR + r0 + t], tred[t]);
    }
  } else {
    // write path: e -> LDS P-tile (swizzled), coalesced fp8 readout + Zw
    u16* __restrict__ Plds = &SMEM[0][0];  // [256][256] u16 = 128KB
    #pragma unroll
    for (int m = 0; m < 8; ++m) {
      #pragma unroll
      for (int j = 0; j < 4; ++j) {
        const int rloc = wm * 128 + m * 16 + lg * 4 + j;
        #pragma unroll
        for (int n = 0; n < 4; ++n) {
          const int col = wn * 64 + n * 16 + lr;
          const int ch = (col >> 3) ^ (rloc & 7);
          Plds[rloc * 256 + ch * 8 + (col & 7)] = f2bf(__expf(acc[m][n][j]));
        }
      }
    }
    __syncthreads();
    u8* __restrict__ pout8 = (u8*)pout;
    #pragma unroll 2
    for (int it = 0; it < 8; ++it) {
      const int row = w * 32 + it * 4 + (l >> 4);
      const int c2 = (l & 15) * 2;        // two consecutive 8-col chunks
      const bf16x8 e0 = *(const bf16x8*)&Plds[row * 256 + ((c2 ^ (row & 7)) * 8)];
      const bf16x8 e1 = *(const bf16x8*)&Plds[row * 256 + (((c2 + 1) ^ (row & 7)) * 8)];
      float ze = 0.f;
      uint4 fb;
      unsigned wds[4] = {0, 0, 0, 0};
      #pragma unroll
      for (int q = 0; q < 8; ++q) {
        const float ea = bf2f((u16)e0[q]);
        const float eb = bf2f((u16)e1[q]);
        ze += ea + eb;
        wds[q >> 2] |= ((unsigned)f8enc(ea)) << ((q & 3) * 8);
        wds[2 + (q >> 2)] |= ((unsigned)f8enc(eb)) << ((q & 3) * 8);
      }
      fb.x = wds[0]; fb.y = wds[1]; fb.z = wds[2]; fb.w = wds[3];
      *(uint4*)&pout8[(r0 + row) * S_ + c0 + (size_t)(l & 15) * 16] = fb;
      #pragma unroll
      for (int off = 1; off < 16; off <<= 1) ze += __shfl_xor(ze, off);
      if ((l & 15) == 0) atomicAdd(&ws[WS_ZW + r0 + row], ze);
    }
  }
}

// PV: V[b][d] += sum_s P[b][s]*memT[d][s]; grid (B/64, 32 k-splits), 256 thr
__global__ void k_pv(const u16* __restrict__ P, const u16* __restrict__ mT,
                     float* __restrict__ ws) {
  __shared__ float Vs[64 * 64];
  const int t = threadIdx.x;
  const int w = t >> 6, l = t & 63;
  const int lr = l & 15, lg = l >> 4;
  const size_t r0 = (size_t)blockIdx.x * 64;
  const size_t s0 = (size_t)blockIdx.y * 1024 + (size_t)w * 256;
  f32x4 acc[4][4];
  #pragma unroll
  for (int m = 0; m < 4; ++m)
    #pragma unroll
    for (int n = 0; n < 4; ++n) acc[m][n] = (f32x4)0.f;

  for (int ks = 0; ks < 8; ++ks) {
    const size_t sb = s0 + ks * 32 + lg * 8;
    bf16x8 a[4], b[4];
    #pragma unroll
    for (int m = 0; m < 4; ++m)
      a[m] = *(const bf16x8*)&P[(r0 + m * 16 + lr) * S_ + sb];
    #pragma unroll
    for (int n = 0; n < 4; ++n)
      b[n] = *(const bf16x8*)&mT[(size_t)(n * 16 + lr) * S_ + sb];
    #pragma unroll
    for (int m = 0; m < 4; ++m)
      #pragma unroll
      for (int n = 0; n < 4; ++n)
        acc[m][n] = __builtin_amdgcn_mfma_f32_16x16x32_bf16(a[m], b[n], acc[m][n], 0, 0, 0);
  }
  for (int i = t; i < 4096; i += 256) Vs[i] = 0.f;
  __syncthreads();
  #pragma unroll
  for (int m = 0; m < 4; ++m)
    #pragma unroll
    for (int j = 0; j < 4; ++j)
      #pragma unroll
      for (int n = 0; n < 4; ++n)
        atomicAdd(&Vs[(m * 16 + lg * 4 + j) * 64 + n * 16 + lr], acc[m][n][j]);
  __syncthreads();
  for (int i = t; i < 4096; i += 256)
    atomicAdd(&ws[WS_VR + (r0 + (size_t)(i >> 6)) * 64 + (i & 63)], Vs[i]);
}

// merged: rc normalize (from WS_VR) + cboost; block 512 does pcmean
__global__ void k_rc2cb(const float* __restrict__ Wcp, const float* __restrict__ bcp,
                        const float* __restrict__ Wce, const float* __restrict__ bce,
                        float* __restrict__ ws,
                        float* __restrict__ out_rc, float* __restrict__ out_cb) {
  const int t = threadIdx.x;
  if (blockIdx.x == 512) {
    __shared__ float red[4][64];
    const int d = t & 63, kk = t >> 6;
    float acc = 0.f;
    #pragma unroll 8
    for (int k = kk * 256; k < kk * 256 + 256; ++k)
      acc = fmaf(ws[WS_CMM + k], Wcp[(size_t)k * D_ + d], acc);
    red[kk][d] = acc;
    __syncthreads();
    if (t < 64) {
      float a = bcp[t];
      #pragma unroll
      for (int i = 0; i < 4; ++i) a += red[i][t];
      ws[WS_PCMEAN + t] = a;
    }
    return;
  }
  __shared__ float rcs[4][64];
  const int idx = blockIdx.x * 256 + t;
  const int b = idx >> 6, d = idx & 63;
  const float rcv = ws[WS_VR + idx] / (ws[WS_TR + b] + 1e-6f * ws[WS_ZR + b]);
  out_rc[idx] = rcv;
  rcs[t >> 6][d] = rcv;
  __syncthreads();
  const int b0 = blockIdx.x * 4;
  #pragma unroll
  for (int oo = 0; oo < 4; ++oo) {
    const int h = oo * 256 + t;
    float a0 = bce[h], a1 = a0, a2 = a0, a3 = a0;
    #pragma unroll 8
    for (int dd = 0; dd < 64; ++dd) {
      const float wv = Wce[(size_t)dd * H_ + h];
      a0 = fmaf(rcs[0][dd], wv, a0);
      a1 = fmaf(rcs[1][dd], wv, a1);
      a2 = fmaf(rcs[2][dd], wv, a2);
      a3 = fmaf(rcs[3][dd], wv, a3);
    }
    out_cb[(size_t)(b0 + 0) * H_ + h] = a0;
    out_cb[(size_t)(b0 + 1) * H_ + h] = a1;
    out_cb[(size_t)(b0 + 2) * H_ + h] = a2;
    out_cb[(size_t)(b0 + 3) * H_ + h] = a3;
  }
}

// ================= shared small kernels =================

// ww_mean from fp8 e-buffer
__global__ void k_wwm_f8(const u8* __restrict__ ebuf, float* __restrict__ ws) {
  const int t = threadIdx.x;
  const int s0 = blockIdx.x * 4096 + t * 16;       // gridx = 8
  const int b0 = blockIdx.y * 128;                 // gridy = 16
  float ww[16];
  #pragma unroll
  for (int j = 0; j < 16; ++j) ww[j] = 0.f;
  #pragma unroll 1
  for (int b = 0; b < 128; ++b) {
    const float inv = 1.0f / ws[WS_ZW + b0 + b];
    const uint4 v = *reinterpret_cast<const uint4*>(&ebuf[(size_t)(b0 + b) * S_ + s0]);
    const unsigned vv[4] = {v.x, v.y, v.z, v.w};
    #pragma unroll
    for (int j = 0; j < 16; ++j) {
      const u8 byte = (u8)((vv[j >> 2] >> ((j & 3) * 8)) & 0xFF);
      ww[j] = fmaf(f8dec(byte), inv, ww[j]);
    }
  }
  #pragma unroll
  for (int j = 0; j < 16; ++j) atomicAdd(&ws[WS_WWM + s0 + j], ww[j]);
}

__global__ void k_final(const float* __restrict__ mem, const float* __restrict__ age,
                        const float* __restrict__ strength, const float* __restrict__ ws,
                        float* __restrict__ out_mem, float* __restrict__ out_age,
                        float* __restrict__ out_str) {
  const int idx = blockIdx.x * 256 + threadIdx.x;
  const int s = idx >> 6, dd = idx & 63;
  const float cm = ws[WS_CMEAN];
  const float w = ws[WS_WWM + s] * (2.0f * cm / B_);
  const bool mask = (w > 0.005f) && (cm >= 0.3f);
  float m = mem[idx];
  if (mask) {
    const float cons = 1.0f / (1.0f + __expf(-(age[s] * 0.1f + cm)));
    const float alpha = w * cons;
    m = (1.0f - alpha) * m + alpha * ws[WS_PCMEAN + dd];
  }
  out_mem[idx] = m;
  if (dd == 0) {
    out_age[s] = age[s] + (mask ? 1.0f : 0.0f);
    out_str[s] = mask ? fminf(fmaxf(strength[s] + w * 0.1f, 0.1f), 2.0f) : strength[s];
  }
}

// ================= FALLBACK PATH (fp32, round-1, known-passing) =================

__global__ void k_stats(const float* __restrict__ content,
                        const float* __restrict__ cl, float* __restrict__ ws) {
  const int gx = blockIdx.x, gy = blockIdx.y, t = threadIdx.x;
  if (gx < 4) {
    const int h = gx * 256 + t;
    const int b0 = gy * 64;
    float acc = 0.f;
    #pragma unroll 8
    for (int b = 0; b < 64; ++b) acc += content[(size_t)(b0 + b) * H_ + h];
    atomicAdd(&ws[WS_CMM + h], acc * (1.0f / B_));
  } else if (t < 64) {
    float acc = cl[gy * 64 + t];
    #pragma unroll
    for (int off = 32; off > 0; off >>= 1) acc += __shfl_down(acc, off);
    if (t == 0) atomicAdd(&ws[WS_CMEAN], acc * (1.0f / B_));
  }
}

__global__ void k_pcmean(const float* __restrict__ Wcp, const float* __restrict__ bcp,
                         float* __restrict__ ws) {
  __shared__ float red[16][64];
  const int t = threadIdx.x, d = t & 63, kk = t >> 6;
  float acc = 0.f;
  const int k0 = kk * 64;
  #pragma unroll 8
  for (int k = k0; k < k0 + 64; ++k)
    acc = fmaf(ws[WS_CMM + k], Wcp[(size_t)k * D_ + d], acc);
  red[kk][d] = acc;
  __syncthreads();
  if (t < 64) {
    float a = bcp[t];
    #pragma unroll
    for (int i = 0; i < 16; ++i) a += red[i][t];
    ws[WS_PCMEAN + t] = a;
  }
}

template <int NR>
__device__ __forceinline__ void logits_kloop(const float* __restrict__ q, int row0,
                                             const float* __restrict__ W, int s,
                                             float* acc) {
  #pragma unroll 1
  for (int k = 0; k < H_; k += 4) {
    const float w0 = W[(size_t)(k + 0) * S_ + s];
    const float w1 = W[(size_t)(k + 1) * S_ + s];
    const float w2 = W[(size_t)(k + 2) * S_ + s];
    const float w3 = W[(size_t)(k + 3) * S_ + s];
    #pragma unroll
    for (int r = 0; r < NR; ++r) {
      const float4 qv = *reinterpret_cast<const float4*>(&q[(size_t)(row0 + r) * H_ + k]);
      float a = acc[r];
      a = fmaf(qv.x, w0, a);
      a = fmaf(qv.y, w1, a);
      a = fmaf(qv.z, w2, a);
      a = fmaf(qv.w, w3, a);
      acc[r] = a;
    }
  }
}

__global__ __launch_bounds__(512, 2) void k_read(
    const float* __restrict__ q, const float* __restrict__ cl,
    const float* __restrict__ Wr, const float* __restrict__ br,
    const float* __restrict__ strength, const float* __restrict__ mem,
    float* __restrict__ ws) {
  __shared__ float plds[BT * 512];
  const int t = threadIdx.x;
  const int r0 = blockIdx.x * BT;
  const int squar = blockIdx.y;
  const int d = t & 63, wv = t >> 6;

  float zacc[BT], tacc[BT];
  #pragma unroll
  for (int r = 0; r < BT; ++r) { zacc[r] = 0.f; tacc[r] = 0.f; }
  float vacc[4] = {0.f, 0.f, 0.f, 0.f};

  for (int tile = 0; tile < 16; ++tile) {
    const int sg0 = squar * 8192 + tile * 512;
    const int s = sg0 + t;
    float acc[BT];
    const float wlast = Wr[(size_t)H_ * S_ + s];
    const float bias = br[s];
    #pragma unroll
    for (int r = 0; r < BT; ++r) acc[r] = fmaf(cl[r0 + r], wlast, bias);
    logits_kloop<BT>(q, r0, Wr, s, acc);

    const float stg = strength[s];
    #pragma unroll
    for (int r = 0; r < BT; ++r) {
      const float e = __expf(acc[r]);
      zacc[r] += e;
      const float p = e * stg;
      tacc[r] += p;
      plds[r * 512 + t] = p;
    }
    __syncthreads();
    #pragma unroll 1
    for (int sl = 0; sl < 512; sl += 4) {
      const float m0 = mem[(size_t)(sg0 + sl + 0) * D_ + d];
      const float m1 = mem[(size_t)(sg0 + sl + 1) * D_ + d];
      const float m2 = mem[(size_t)(sg0 + sl + 2) * D_ + d];
      const float m3 = mem[(size_t)(sg0 + sl + 3) * D_ + d];
      #pragma unroll
      for (int j = 0; j < 4; ++j) {
        const float4 pv = *reinterpret_cast<const float4*>(&plds[(wv + 8 * j) * 512 + sl]);
        float v = vacc[j];
        v = fmaf(pv.x, m0, v);
        v = fmaf(pv.y, m1, v);
        v = fmaf(pv.z, m2, v);
        v = fmaf(pv.w, m3, v);
        vacc[j] = v;
      }
    }
    __syncthreads();
  }

  float* red0 = plds;
  float* red1 = plds + 8 * BT;
  #pragma unroll
  for (int r = 0; r < BT; ++r) {
    float z = zacc[r], tt = tacc[r];
    #pragma unroll
    for (int off = 32; off > 0; off >>= 1) {
      z += __shfl_down(z, off);
      tt += __shfl_down(tt, off);
    }
    if ((t & 63) == 0) { red0[wv * BT + r] = z; red1[wv * BT + r] = tt; }
  }
  __syncthreads();
  if (t < BT) {
    float z = 0.f, tt = 0.f;
    #pragma unroll
    for (int wq = 0; wq < 8; ++wq) { z += red0[wq * BT + t]; tt += red1[wq * BT + t]; }
    atomicAdd(&ws[WS_ZR + r0 + t], z);
    atomicAdd(&ws[WS_TR + r0 + t], tt);
  }
  #pragma unroll
  for (int j = 0; j < 4; ++j)
    atomicAdd(&ws[WS_VR + (size_t)(r0 + wv + 8 * j) * D_ + d], vacc[j]);
}

__global__ __launch_bounds__(512, 2) void k_write_pass1(
    const float* __restrict__ q, const float* __restrict__ cl,
    const float* __restrict__ Ww, const float* __restrict__ bw,
    float* __restrict__ ws, __hip_bfloat16* __restrict__ ebuf, const int store_e) {
  __shared__ float red[8 * BT];
  const int t = threadIdx.x;
  const int r0 = blockIdx.x * BT;
  const int squar = blockIdx.y;
  const int wv = t >> 6;

  float zacc[BT];
  #pragma unroll
  for (int r = 0; r < BT; ++r) zacc[r] = 0.f;

  for (int tile = 0; tile < 16; ++tile) {
    const int s = squar * 8192 + tile * 512 + t;
    float acc[BT];
    const float wlast = Ww[(size_t)H_ * S_ + s];
    const float bias = bw[s];
    #pragma unroll
    for (int r = 0; r < BT; ++r) acc[r] = fmaf(cl[r0 + r], wlast, bias);
    logits_kloop<BT>(q, r0, Ww, s, acc);
    #pragma unroll
    for (int r = 0; r < BT; ++r) {
      const float e = __expf(acc[r]);
      zacc[r] += e;
      if (store_e) ebuf[(size_t)(r0 + r) * S_ + s] = __float2bfloat16(e);
    }
  }
  #pragma unroll
  for (int r = 0; r < BT; ++r) {
    float z = zacc[r];
    #pragma unroll
    for (int off = 32; off > 0; off >>= 1) z += __shfl_down(z, off);
    if ((t & 63) == 0) red[wv * BT + r] = z;
  }
  __syncthreads();
  if (t < BT) {
    float z = 0.f;
    #pragma unroll
    for (int wq = 0; wq < 8; ++wq) z += red[wq * BT + t];
    atomicAdd(&ws[WS_ZW + r0 + t], z);
  }
}

__global__ void k_rc(const float* __restrict__ ws, float* __restrict__ out) {
  const int idx = blockIdx.x * 256 + threadIdx.x;
  const int b = idx >> 6;
  const float z = ws[WS_ZR + b], tt = ws[WS_TR + b];
  out[idx] = ws[WS_VR + idx] / (tt + 1e-6f * z);
}

__global__ void k_cboost(const float* __restrict__ rc, const float* __restrict__ Wce,
                         const float* __restrict__ bce, float* __restrict__ out) {
  const int idx = blockIdx.x * 256 + threadIdx.x;
  const int b = idx >> 10, h = idx & 1023;
  const float* __restrict__ rcb = &rc[b * 64];
  float acc = bce[h];
  #pragma unroll
  for (int dd = 0; dd < 64; dd += 4) {
    const float4 r4 = *reinterpret_cast<const float4*>(&rcb[dd]);
    acc = fmaf(r4.x, Wce[(size_t)(dd + 0) * H_ + h], acc);
    acc = fmaf(r4.y, Wce[(size_t)(dd + 1) * H_ + h], acc);
    acc = fmaf(r4.z, Wce[(size_t)(dd + 2) * H_ + h], acc);
    acc = fmaf(r4.w, Wce[(size_t)(dd + 3) * H_ + h], acc);
  }
  out[idx] = acc;
}

__global__ void k_wwm_store(const __hip_bfloat16* __restrict__ ebuf,
                            float* __restrict__ ws) {
  const int t = threadIdx.x;
  const int s0 = blockIdx.x * 2048 + t * 8;
  const int b0 = blockIdx.y * 128;
  const u16* __restrict__ eb = (const u16*)ebuf;
  float ww[8];
  #pragma unroll
  for (int j = 0; j < 8; ++j) ww[j] = 0.f;
  #pragma unroll 1
  for (int b = 0; b < 128; ++b) {
    const float inv = 1.0f / ws[WS_ZW + b0 + b];
    const ushort8v ev = *reinterpret_cast<const ushort8v*>(&eb[(size_t)(b0 + b) * S_ + s0]);
    #pragma unroll
    for (int j = 0; j < 8; ++j) {
      const float e = __uint_as_float(((unsigned)ev[j]) << 16);
      ww[j] = fmaf(e, inv, ww[j]);
    }
  }
  #pragma unroll
  for (int j = 0; j < 8; ++j) atomicAdd(&ws[WS_WWM + s0 + j], ww[j]);
}

__global__ __launch_bounds__(512, 2) void k_wwm_recompute(
    const float* __restrict__ q, const float* __restrict__ cl,
    const float* __restrict__ Ww, const float* __restrict__ bw,
    float* __restrict__ ws) {
  const int t = threadIdx.x;
  const int s = blockIdx.x * 512 + t;
  const int b0 = blockIdx.y * 256;
  const float wlast = Ww[(size_t)H_ * S_ + s];
  const float bias = bw[s];
  float wwacc = 0.f;
  for (int g = 0; g < 8; ++g) {
    const int rb = b0 + g * 32;
    float acc[BT];
    #pragma unroll
    for (int r = 0; r < BT; ++r) acc[r] = fmaf(cl[rb + r], wlast, bias);
    logits_kloop<BT>(q, rb, Ww, s, acc);
    #pragma unroll
    for (int r = 0; r < BT; ++r) wwacc += __expf(acc[r]) / ws[WS_ZW + rb + r];
  }
  atomicAdd(&ws[WS_WWM + s], wwacc);
}

// ================= launcher =================

extern "C" void kernel_launch(void* const* d_in, const int* in_sizes, int n_in,
                              void* d_out, int out_size, void* d_ws, size_t ws_size,
                              hipStream_t stream) {
  const float* query    = (const float*)d_in[0];
  const float* cl       = (const float*)d_in[1];
  const float* content  = (const float*)d_in[2];
  const float* memory   = (const float*)d_in[3];
  const float* age      = (const float*)d_in[4];
  const float* strength = (const float*)d_in[5];
  const float* W_read   = (const float*)d_in[6];
  const float* b_read   = (const float*)d_in[7];
  const float* W_write  = (const float*)d_in[8];
  const float* b_write  = (const float*)d_in[9];
  const float* W_cp     = (const float*)d_in[10];
  const float* b_cp     = (const float*)d_in[11];
  const float* W_ce     = (const float*)d_in[12];
  const float* b_ce     = (const float*)d_in[13];

  float* out = (float*)d_out;
  float* ws = (float*)d_ws;
  float* out_rc  = out;
  float* out_cb  = out + B_ * D_;
  float* out_mem = out_cb + (size_t)B_ * H_;
  float* out_age = out_mem + (size_t)S_ * D_;
  float* out_str = out_age + S_;

  // fast-path workspace layout (float offsets); pf8 aliases pbuf
  const size_t QB_F    = WS_END;
  const size_t MEMT_F  = QB_F + (size_t)B_ * KQS / 2;
  const size_t WBTR_F  = MEMT_F + (size_t)D_ * S_ / 2;
  const size_t PBUF_F  = WBTR_F + (size_t)S_ * KQS / 2;
  const size_t FAST_END_F = PBUF_F + (size_t)B_ * S_ / 2;   // ~53.2M floats

  hipMemsetAsync(ws, 0, (size_t)WS_END * sizeof(float), stream);

  if (ws_size >= FAST_END_F * sizeof(float)) {
    u16* qb   = (u16*)(ws + QB_F);
    u16* mT   = (u16*)(ws + MEMT_F);
    u16* wbtR = (u16*)(ws + WBTR_F);
    u16* pbuf = (u16*)(ws + PBUF_F);       // gemm<0> P bf16
    u8*  pf8  = (u8*)(ws + PBUF_F);        // gemm<1> fp8 e-buffer (aliased, sequential)

    k_pre<<<160 + B_ + 512 + 8192, 256, 0, stream>>>(
        query, cl, content, memory, W_read, qb, mT, wbtR, ws);
    k_gemm<0><<<dim3(8, 128), 512, 0, stream>>>(qb, wbtR, W_read, b_read, cl,
                                                strength, (void*)pbuf, ws);
    k_cvt_wtW<<<dim3(512, 16), 256, 0, stream>>>(W_write, wbtR);
    k_pv<<<dim3(B_ / 64, 32), 256, 0, stream>>>(pbuf, mT, ws);
    k_rc2cb<<<513, 256, 0, stream>>>(W_cp, b_cp, W_ce, b_ce, ws, out_rc, out_cb);
    k_gemm<1><<<dim3(8, 128), 512, 0, stream>>>(qb, wbtR, W_write, b_write, cl,
                                                nullptr, (void*)pf8, ws);
    k_wwm_f8<<<dim3(8, 16), 256, 0, stream>>>(pf8, ws);
    k_final<<<(S_ * D_) / 256, 256, 0, stream>>>(memory, age, strength, ws,
                                                 out_mem, out_age, out_str);
  } else {
    const size_t ebuf_bytes = (size_t)B_ * S_ * 2;
    const int store_e = (ws_size >= (size_t)WS_END * 4 + ebuf_bytes) ? 1 : 0;
    __hip_bfloat16* ebuf = (__hip_bfloat16*)(ws + WS_END);

    k_stats<<<dim3(5, 32), 256, 0, stream>>>(content, cl, ws);
    k_pcmean<<<1, 1024, 0, stream>>>(W_cp, b_cp, ws);
    k_read<<<dim3(B_ / BT, 4), 512, 0, stream>>>(query, cl, W_read, b_read, strength, memory, ws);
    k_write_pass1<<<dim3(B_ / BT, 4), 512, 0, stream>>>(query, cl, W_write, b_write, ws, ebuf, store_e);
    k_rc<<<(B_ * D_) / 256, 256, 0, stream>>>(ws, out_rc);
    k_cboost<<<(B_ * H_) / 256, 256, 0, stream>>>(out_rc, W_ce, b_ce, out_cb);
    if (store_e) {
      k_wwm_store<<<dim3(S_ / 2048, B_ / 128), 256, 0, stream>>>(ebuf, ws);
    } else {
      k_wwm_recompute<<<dim3(S_ / 512, 8), 512, 0, stream>>>(query, cl, W_write, b_write, ws);
    }
    k_final<<<(S_ * D_) / 256, 256, 0, stream>>>(memory, age, strength, ws,
                                                 out_mem, out_age, out_str);
  }
}

// Round 9
// 724.386 us; speedup vs baseline: 1.0507x; 1.0507x over previous
//
#include <hip/hip_runtime.h>
#include <hip/hip_bf16.h>
#include <cstdint>
#include <cstddef>

#define B_ 2048
#define H_ 1024
#define S_ 32768
#define D_ 64
#define BT 32
#define KQ 1024   // GEMM K (query only); cl & bias folded into fp32 epilogue
#define KQS 1056  // stored row stride in u16 (2112B, non-power-of-2)
#define NT 16     // K-tiles of 64

typedef unsigned char u8;
typedef unsigned short u16;
typedef __attribute__((ext_vector_type(8))) short bf16x8;
typedef __attribute__((ext_vector_type(8))) unsigned short ushort8v;
typedef __attribute__((ext_vector_type(4))) float f32x4;

// workspace layout (float offsets) -- shared by fast + fallback paths
#define WS_CMEAN      0
#define WS_PCMEAN     64
#define WS_CMM        128                    // content mean [H]
#define WS_ZR         (WS_CMM + H_)          // [B]
#define WS_TR         (WS_ZR + B_)           // [B]
#define WS_VR         (WS_TR + B_)           // [B*D] (fallback only)
#define WS_ZW         (WS_VR + B_*D_)        // [B]
#define WS_WWM        (WS_ZW + B_)           // [S]
#define WS_END        (WS_WWM + S_)          // 171136 floats

__device__ __forceinline__ u16 f2bf(float f) {
  unsigned u = __float_as_uint(f);
  unsigned r = (u + 0x7FFFu + ((u >> 16) & 1u)) >> 16;
  return (u16)r;
}

__device__ __forceinline__ float bf2f(u16 v) {
  return __uint_as_float(((unsigned)v) << 16);
}

// fp8 e4m3fn encode (f > 0, clamped to 448), RNE
__device__ __forceinline__ u8 f8enc(float f) {
  f = fminf(f, 448.f);
  unsigned u = __float_as_uint(f);
  int ex = (int)((u >> 23) & 255) - 127;
  unsigned r;
  if (ex >= -6) {
    unsigned m = u & 0x7FFFFF;
    unsigned rm = (m + 0x7FFFF + ((m >> 20) & 1)) >> 20;
    r = ((unsigned)(ex + 7) << 3) + rm;
  } else {
    r = (unsigned)fminf(7.f, f * 512.f + 0.5f);
  }
  return (u8)(r > 126 ? 126 : r);
}

__device__ __forceinline__ float f8dec(u8 b) {
  int ef = (b >> 3) & 15, m = b & 7;
  return ef ? __uint_as_float(((unsigned)(ef + 120) << 23) | ((unsigned)m << 20))
            : (float)m * 0.001953125f;
}

__device__ __forceinline__ void gload_lds16(const void* g, void* l) {
  __builtin_amdgcn_global_load_lds(
      (const __attribute__((address_space(1))) unsigned int*)g,
      (__attribute__((address_space(3))) unsigned int*)l, 16, 0, 0);
}

// ================= FAST PATH =================

// merged preprocessing: stats + cvt_q + cvt_memT + cvt_wt(read) + cvt_wt(write)
// grid sections (256 thr): [0,128) content-mean, [128,160) cl-mean,
// [160,2208) qb cast, [2208,2720) memT, [2720,10912) wbtR, [10912,19104) wbtW
__global__ void k_pre(const float* __restrict__ query, const float* __restrict__ cl,
                      const float* __restrict__ content, const float* __restrict__ mem,
                      const float* __restrict__ Wr, const float* __restrict__ Ww,
                      u16* __restrict__ qb, u16* __restrict__ mT,
                      u16* __restrict__ wbtR, u16* __restrict__ wbtW,
                      float* __restrict__ ws) {
  const int blk = blockIdx.x, t = threadIdx.x;
  if (blk < 128) {
    const int h = (blk & 3) * 256 + t;
    const int b0 = (blk >> 2) * 64;
    float acc = 0.f;
    #pragma unroll 8
    for (int b = 0; b < 64; ++b) acc += content[(size_t)(b0 + b) * H_ + h];
    atomicAdd(&ws[WS_CMM + h], acc * (1.0f / B_));
  } else if (blk < 160) {
    if (t < 64) {
      float acc = cl[(blk - 128) * 64 + t];
      #pragma unroll
      for (int off = 32; off > 0; off >>= 1) acc += __shfl_down(acc, off);
      if (t == 0) atomicAdd(&ws[WS_CMEAN], acc * (1.0f / B_));
    }
  } else if (blk < 160 + B_) {
    const int b = blk - 160;
    const float4 q4 = *reinterpret_cast<const float4*>(&query[(size_t)b * H_ + t * 4]);
    ushort4 o;
    o.x = f2bf(q4.x); o.y = f2bf(q4.y); o.z = f2bf(q4.z); o.w = f2bf(q4.w);
    *reinterpret_cast<ushort4*>(&qb[(size_t)b * KQS + t * 4]) = o;
  } else if (blk < 160 + B_ + 512) {
    __shared__ float tile[64][65];
    const int s0 = (blk - 160 - B_) * 64;
    const int c = t & 63, rbase = t >> 6;
    #pragma unroll
    for (int i = 0; i < 16; ++i) {
      const int r = rbase + i * 4;
      tile[r][c] = mem[(size_t)(s0 + r) * D_ + c];
    }
    __syncthreads();
    #pragma unroll
    for (int i = 0; i < 16; ++i) {
      const int d = rbase + i * 4;
      mT[(size_t)d * S_ + s0 + c] = f2bf(tile[c][d]);
    }
  } else {
    const int base = 160 + B_ + 512;
    const int isW = blk >= base + 8192;
    const int i = blk - base - (isW ? 8192 : 0);
    const float* __restrict__ W = isW ? Ww : Wr;
    u16* __restrict__ wbt = isW ? wbtW : wbtR;
    __shared__ float tile[64][65];
    const int s0 = (i & 511) * 64;
    const int k0 = (i >> 9) * 64;
    const int c = t & 63, rbase = t >> 6;
    #pragma unroll
    for (int j = 0; j < 16; ++j) {
      const int r = rbase + j * 4;
      tile[r][c] = W[(size_t)(k0 + r) * S_ + s0 + c];
    }
    __syncthreads();
    #pragma unroll
    for (int j = 0; j < 16; ++j) {
      const int sr = rbase + j * 4;
      wbt[(size_t)(s0 + sr) * KQS + k0 + c] = f2bf(tile[c][sr]);
    }
  }
}

// LDS frag read: 16x16x32 A/B operand, rows rowbase+f*16+lr, 8-slot XOR swizzle
template <int NF>
__device__ __forceinline__ void rd_frags(const u16* __restrict__ lds, int rowbase,
                                         int lr, int lg, bf16x8 (&dst)[NF * 2]) {
  #pragma unroll
  for (int f = 0; f < NF; ++f) {
    const int rr = rowbase + f * 16 + lr;
    #pragma unroll
    for (int ks = 0; ks < 2; ++ks) {
      const int ch = (ks * 4 + lg) ^ (rr & 7);
      dst[f * 2 + ks] = *(const bf16x8*)&lds[rr * 64 + ch * 8];
    }
  }
}

template <int QR, int QC>
__device__ __forceinline__ void mfmaq(f32x4 (&acc)[8][4], const bf16x8 (&av)[8],
                                      const bf16x8 (&bv)[4]) {
  #pragma unroll
  for (int m16 = 0; m16 < 4; ++m16)
    #pragma unroll
    for (int n16 = 0; n16 < 2; ++n16)
      #pragma unroll
      for (int ks = 0; ks < 2; ++ks)
        acc[QR * 4 + m16][QC * 2 + n16] = __builtin_amdgcn_mfma_f32_16x16x32_bf16(
            av[m16 * 2 + ks], bv[n16 * 2 + ks], acc[QR * 4 + m16][QC * 2 + n16], 0, 0, 0);
}

// Fused bf16 MFMA GEMM, 8-phase/counted-vmcnt schedule, K=1024 (NT=16),
// stored stride KQS=1056 u16 (non-power-of-2).
// logit = (qb @ wbt^T)[r][c] + cl[r]*W[1024][c] + bias[c] (fp32 epilogue add).
//  VARIANT 0 (read): p=e*strength -> LDS P-tile; Z/T row atomics; fused PV
//    (each wave owns a 32-row slice, contracts all 256 s vs memT);
//    fp32 V-partials -> vp[cblk][B][64] (pout).
//  VARIANT 1 (write): e -> LDS, coalesced fp8 e4m3 readout -> pout, Zw atomics.
// Block 512 thr (8 waves 2Mx4N), tile 256x256, BK=64, LDS 128KB.
template <int VARIANT>
__global__ __launch_bounds__(512, 2) void k_gemm(
    const u16* __restrict__ qb, const u16* __restrict__ wbt,
    const float* __restrict__ Wfull, const float* __restrict__ biasv,
    const float* __restrict__ cl, const float* __restrict__ strength,
    const u16* __restrict__ mT, void* __restrict__ pout, float* __restrict__ ws) {
  __shared__ __align__(16) u16 SMEM[4][256 * 64];  // [0..1]=A dbuf, [2..3]=B dbuf
  const int t = threadIdx.x;
  const int w = t >> 6, l = t & 63;
  const int wm = w >> 2, wn = w & 3;          // 2 x 4 waves
  const int lr = l & 15, lg = l >> 4;

  // bijective XCD-chunked remap: each XCD owns 16 contiguous col-blocks
  const int lin = blockIdx.x + 8 * blockIdx.y;   // gridDim = (8, 128)
  const int xcd = lin & 7, idx = lin >> 3;
  const size_t r0 = (size_t)(idx & 7) * 256;
  const int cblk = xcd * 16 + (idx >> 3);
  const size_t c0 = (size_t)cblk * 256;

  f32x4 acc[8][4];
  #pragma unroll
  for (int m = 0; m < 8; ++m)
    #pragma unroll
    for (int n = 0; n < 4; ++n) acc[m][n] = (f32x4)0.f;

  // stage K-tile kt2 into buffer pp: 8 gloads/thread, source pre-swizzled
  auto STAGE = [&](int kt2, int pp) {
    #pragma unroll
    for (int i = 0; i < 4; ++i) {
      const int q = i * 512 + t;
      const int r = q >> 3;
      const int sc = (q & 7) ^ (r & 7);
      gload_lds16(qb + (r0 + r) * KQS + (size_t)kt2 * 64 + sc * 8, &SMEM[pp][q * 8]);
    }
    #pragma unroll
    for (int i = 0; i < 4; ++i) {
      const int q = i * 512 + t;
      const int r = q >> 3;
      const int sc = (q & 7) ^ (r & 7);
      gload_lds16(wbt + (c0 + r) * KQS + (size_t)kt2 * 64 + sc * 8, &SMEM[2 + pp][q * 8]);
    }
  };

  // prologue: 2 K-tiles in flight
  STAGE(0, 0);
  STAGE(1, 1);
  asm volatile("s_waitcnt vmcnt(8)" ::: "memory");   // kt0 arrived, kt1 flying
  __builtin_amdgcn_sched_barrier(0);
  __builtin_amdgcn_s_barrier();

  for (int kt = 0; kt < NT; ++kt) {
    const int p = kt & 1;
    const u16* __restrict__ Ap = &SMEM[p][0];
    const u16* __restrict__ Bp = &SMEM[2 + p][0];
    bf16x8 a[8], b0[4], b1[4];
    // phase 1: read A(qr0)+B(qc0); MFMA quadrant (0,0)
    rd_frags<4>(Ap, wm * 128 + 0, lr, lg, a);
    rd_frags<2>(Bp, wn * 64 + 0, lr, lg, b0);
    __builtin_amdgcn_sched_barrier(0);
    __builtin_amdgcn_s_barrier();
    __builtin_amdgcn_s_setprio(1);
    mfmaq<0, 0>(acc, a, b0);
    __builtin_amdgcn_s_setprio(0);
    __builtin_amdgcn_s_barrier();
    // phase 2: read B(qc1); MFMA (0,1)
    rd_frags<2>(Bp, wn * 64 + 32, lr, lg, b1);
    __builtin_amdgcn_sched_barrier(0);
    __builtin_amdgcn_s_barrier();
    __builtin_amdgcn_s_setprio(1);
    mfmaq<0, 1>(acc, a, b1);
    __builtin_amdgcn_s_setprio(0);
    __builtin_amdgcn_s_barrier();
    // phase 3: read A(qr1); MFMA (1,1)
    rd_frags<4>(Ap, wm * 128 + 64, lr, lg, a);
    __builtin_amdgcn_sched_barrier(0);
    __builtin_amdgcn_s_barrier();
    __builtin_amdgcn_s_setprio(1);
    mfmaq<1, 1>(acc, a, b1);
    __builtin_amdgcn_s_setprio(0);
    __builtin_amdgcn_s_barrier();
    // phase 4: buf[p] LDS fully consumed -> stage kt+2 into it; MFMA (1,0) from regs
    if (kt + 2 < NT) STAGE(kt + 2, p);
    __builtin_amdgcn_s_barrier();
    __builtin_amdgcn_s_setprio(1);
    mfmaq<1, 0>(acc, a, b0);
    __builtin_amdgcn_s_setprio(0);
    if (kt + 2 < NT) {
      asm volatile("s_waitcnt vmcnt(8)" ::: "memory");   // kt+1 arrived, kt+2 flying
    } else if (kt + 1 < NT) {
      asm volatile("s_waitcnt vmcnt(0)" ::: "memory");   // tail drain
    }
    __builtin_amdgcn_sched_barrier(0);
    __builtin_amdgcn_s_barrier();
  }

  // ---------- epilogue ----------
  // C/D layout: col=lane&15, row=(lane>>4)*4+reg
  // fp32 rank-1 adjust: logit += cl[row]*W[1024][col] + bias[col]
  float wl4[4], bb4[4];
  #pragma unroll
  for (int n = 0; n < 4; ++n) {
    const size_t col = c0 + wn * 64 + n * 16 + lr;
    wl4[n] = Wfull[(size_t)H_ * S_ + col];
    bb4[n] = biasv[col];
  }
  #pragma unroll
  for (int m = 0; m < 8; ++m) {
    #pragma unroll
    for (int j = 0; j < 4; ++j) {
      const float clv = cl[r0 + wm * 128 + m * 16 + lg * 4 + j];
      #pragma unroll
      for (int n = 0; n < 4; ++n)
        acc[m][n][j] += fmaf(clv, wl4[n], bb4[n]);
    }
  }

  u16* __restrict__ Plds = &SMEM[0][0];   // [256][256] u16 = 128KB (all 4 buffers)

  if (VARIANT == 0) {
    // p = e*strength -> LDS P-tile; Z/T from registers
    float st4[4];
    #pragma unroll
    for (int n = 0; n < 4; ++n) st4[n] = strength[c0 + wn * 64 + n * 16 + lr];
    #pragma unroll
    for (int m = 0; m < 8; ++m) {
      #pragma unroll
      for (int j = 0; j < 4; ++j) {
        const int rloc = wm * 128 + m * 16 + lg * 4 + j;
        float ze = 0.f, zp = 0.f;
        #pragma unroll
        for (int n = 0; n < 4; ++n) {
          const float e = __expf(acc[m][n][j]);
          const float pq = e * st4[n];
          ze += e;
          zp += pq;
          const int col = wn * 64 + n * 16 + lr;
          const int ch = (col >> 3) ^ (rloc & 7);
          Plds[rloc * 256 + ch * 8 + (col & 7)] = f2bf(pq);
        }
        #pragma unroll
        for (int off = 1; off < 16; off <<= 1) {
          ze += __shfl_xor(ze, off);
          zp += __shfl_xor(zp, off);
        }
        if (lr == 0) {
          atomicAdd(&ws[WS_ZR + r0 + rloc], ze);
          atomicAdd(&ws[WS_TR + r0 + rloc], zp);
        }
      }
    }
    __syncthreads();
    // fused PV: wave w owns rows w*32..w*32+32, contracts over all 256 s
    float* __restrict__ vp = (float*)pout;
    f32x4 pv[2][4];
    #pragma unroll
    for (int f = 0; f < 2; ++f)
      #pragma unroll
      for (int n = 0; n < 4; ++n) pv[f][n] = (f32x4)0.f;
    #pragma unroll 2
    for (int ks = 0; ks < 8; ++ks) {
      bf16x8 pa[2], pb[4];
      #pragma unroll
      for (int f = 0; f < 2; ++f) {
        const int row = w * 32 + f * 16 + lr;
        const int ch = (ks * 4 + lg) ^ (row & 7);
        pa[f] = *(const bf16x8*)&Plds[row * 256 + ch * 8];
      }
      #pragma unroll
      for (int n = 0; n < 4; ++n)
        pb[n] = *(const bf16x8*)&mT[(size_t)(n * 16 + lr) * S_ + c0 + ks * 32 + lg * 8];
      #pragma unroll
      for (int f = 0; f < 2; ++f)
        #pragma unroll
        for (int n = 0; n < 4; ++n)
          pv[f][n] = __builtin_amdgcn_mfma_f32_16x16x32_bf16(pa[f], pb[n], pv[f][n], 0, 0, 0);
    }
    // store fp32 V-partials: vp[cblk][r0 + w*32 + row][d]
    #pragma unroll
    for (int f = 0; f < 2; ++f) {
      #pragma unroll
      for (int j = 0; j < 4; ++j) {
        const size_t R = (size_t)cblk * B_ + r0 + w * 32 + f * 16 + lg * 4 + j;
        #pragma unroll
        for (int n = 0; n < 4; ++n)
          vp[R * 64 + n * 16 + lr] = pv[f][n][j];
      }
    }
  } else {
    // write path: e -> LDS, coalesced fp8 readout + Zw
    #pragma unroll
    for (int m = 0; m < 8; ++m) {
      #pragma unroll
      for (int j = 0; j < 4; ++j) {
        const int rloc = wm * 128 + m * 16 + lg * 4 + j;
        #pragma unroll
        for (int n = 0; n < 4; ++n) {
          const int col = wn * 64 + n * 16 + lr;
          const int ch = (col >> 3) ^ (rloc & 7);
          Plds[rloc * 256 + ch * 8 + (col & 7)] = f2bf(__expf(acc[m][n][j]));
        }
      }
    }
    __syncthreads();
    u8* __restrict__ pout8 = (u8*)pout;
    #pragma unroll 2
    for (int it = 0; it < 8; ++it) {
      const int row = w * 32 + it * 4 + (l >> 4);
      const int c2 = (l & 15) * 2;        // two consecutive 8-col chunks
      const bf16x8 e0 = *(const bf16x8*)&Plds[row * 256 + ((c2 ^ (row & 7)) * 8)];
      const bf16x8 e1 = *(const bf16x8*)&Plds[row * 256 + (((c2 + 1) ^ (row & 7)) * 8)];
      float ze = 0.f;
      uint4 fb;
      unsigned wds[4] = {0, 0, 0, 0};
      #pragma unroll
      for (int q = 0; q < 8; ++q) {
        const float ea = bf2f((u16)e0[q]);
        const float eb = bf2f((u16)e1[q]);
        ze += ea + eb;
        wds[q >> 2] |= ((unsigned)f8enc(ea)) << ((q & 3) * 8);
        wds[2 + (q >> 2)] |= ((unsigned)f8enc(eb)) << ((q & 3) * 8);
      }
      fb.x = wds[0]; fb.y = wds[1]; fb.z = wds[2]; fb.w = wds[3];
      *(uint4*)&pout8[(r0 + row) * S_ + c0 + (size_t)(l & 15) * 16] = fb;
      #pragma unroll
      for (int off = 1; off < 16; off <<= 1) ze += __shfl_xor(ze, off);
      if ((l & 15) == 0) atomicAdd(&ws[WS_ZW + r0 + row], ze);
    }
  }
}

// merged: V-partial reduce + rc normalize + cboost; block 512 does pcmean
__global__ void k_rc2cb(const float* __restrict__ vp, const float* __restrict__ Wcp,
                        const float* __restrict__ bcp, const float* __restrict__ Wce,
                        const float* __restrict__ bce, float* __restrict__ ws,
                        float* __restrict__ out_rc, float* __restrict__ out_cb) {
  const int t = threadIdx.x;
  if (blockIdx.x == 512) {
    __shared__ float red[4][64];
    const int d = t & 63, kk = t >> 6;
    float acc = 0.f;
    #pragma unroll 8
    for (int k = kk * 256; k < kk * 256 + 256; ++k)
      acc = fmaf(ws[WS_CMM + k], Wcp[(size_t)k * D_ + d], acc);
    red[kk][d] = acc;
    __syncthreads();
    if (t < 64) {
      float a = bcp[t];
      #pragma unroll
      for (int i = 0; i < 4; ++i) a += red[i][t];
      ws[WS_PCMEAN + t] = a;
    }
    return;
  }
  __shared__ float rcs[4][64];
  const int idx = blockIdx.x * 256 + t;
  const int b = idx >> 6, d = idx & 63;
  float v = 0.f;
  #pragma unroll 4
  for (int c = 0; c < 128; ++c) v += vp[(size_t)c * B_ * 64 + idx];
  const float rcv = v / (ws[WS_TR + b] + 1e-6f * ws[WS_ZR + b]);
  out_rc[idx] = rcv;
  rcs[t >> 6][d] = rcv;
  __syncthreads();
  const int b0 = blockIdx.x * 4;
  #pragma unroll
  for (int oo = 0; oo < 4; ++oo) {
    const int h = oo * 256 + t;
    float a0 = bce[h], a1 = a0, a2 = a0, a3 = a0;
    #pragma unroll 8
    for (int dd = 0; dd < 64; ++dd) {
      const float wv = Wce[(size_t)dd * H_ + h];
      a0 = fmaf(rcs[0][dd], wv, a0);
      a1 = fmaf(rcs[1][dd], wv, a1);
      a2 = fmaf(rcs[2][dd], wv, a2);
      a3 = fmaf(rcs[3][dd], wv, a3);
    }
    out_cb[(size_t)(b0 + 0) * H_ + h] = a0;
    out_cb[(size_t)(b0 + 1) * H_ + h] = a1;
    out_cb[(size_t)(b0 + 2) * H_ + h] = a2;
    out_cb[(size_t)(b0 + 3) * H_ + h] = a3;
  }
}

// ================= shared small kernels =================

// ww_mean from fp8 e-buffer
__global__ void k_wwm_f8(const u8* __restrict__ ebuf, float* __restrict__ ws) {
  const int t = threadIdx.x;
  const int s0 = blockIdx.x * 4096 + t * 16;       // gridx = 8
  const int b0 = blockIdx.y * 128;                 // gridy = 16
  float ww[16];
  #pragma unroll
  for (int j = 0; j < 16; ++j) ww[j] = 0.f;
  #pragma unroll 1
  for (int b = 0; b < 128; ++b) {
    const float inv = 1.0f / ws[WS_ZW + b0 + b];
    const uint4 v = *reinterpret_cast<const uint4*>(&ebuf[(size_t)(b0 + b) * S_ + s0]);
    const unsigned vv[4] = {v.x, v.y, v.z, v.w};
    #pragma unroll
    for (int j = 0; j < 16; ++j) {
      const u8 byte = (u8)((vv[j >> 2] >> ((j & 3) * 8)) & 0xFF);
      ww[j] = fmaf(f8dec(byte), inv, ww[j]);
    }
  }
  #pragma unroll
  for (int j = 0; j < 16; ++j) atomicAdd(&ws[WS_WWM + s0 + j], ww[j]);
}

__global__ void k_final(const float* __restrict__ mem, const float* __restrict__ age,
                        const float* __restrict__ strength, const float* __restrict__ ws,
                        float* __restrict__ out_mem, float* __restrict__ out_age,
                        float* __restrict__ out_str) {
  const int idx = blockIdx.x * 256 + threadIdx.x;
  const int s = idx >> 6, dd = idx & 63;
  const float cm = ws[WS_CMEAN];
  const float w = ws[WS_WWM + s] * (2.0f * cm / B_);
  const bool mask = (w > 0.005f) && (cm >= 0.3f);
  float m = mem[idx];
  if (mask) {
    const float cons = 1.0f / (1.0f + __expf(-(age[s] * 0.1f + cm)));
    const float alpha = w * cons;
    m = (1.0f - alpha) * m + alpha * ws[WS_PCMEAN + dd];
  }
  out_mem[idx] = m;
  if (dd == 0) {
    out_age[s] = age[s] + (mask ? 1.0f : 0.0f);
    out_str[s] = mask ? fminf(fmaxf(strength[s] + w * 0.1f, 0.1f), 2.0f) : strength[s];
  }
}

// ================= FALLBACK PATH (fp32, round-1, known-passing) =================

__global__ void k_stats(const float* __restrict__ content,
                        const float* __restrict__ cl, float* __restrict__ ws) {
  const int gx = blockIdx.x, gy = blockIdx.y, t = threadIdx.x;
  if (gx < 4) {
    const int h = gx * 256 + t;
    const int b0 = gy * 64;
    float acc = 0.f;
    #pragma unroll 8
    for (int b = 0; b < 64; ++b) acc += content[(size_t)(b0 + b) * H_ + h];
    atomicAdd(&ws[WS_CMM + h], acc * (1.0f / B_));
  } else if (t < 64) {
    float acc = cl[gy * 64 + t];
    #pragma unroll
    for (int off = 32; off > 0; off >>= 1) acc += __shfl_down(acc, off);
    if (t == 0) atomicAdd(&ws[WS_CMEAN], acc * (1.0f / B_));
  }
}

__global__ void k_pcmean(const float* __restrict__ Wcp, const float* __restrict__ bcp,
                         float* __restrict__ ws) {
  __shared__ float red[16][64];
  const int t = threadIdx.x, d = t & 63, kk = t >> 6;
  float acc = 0.f;
  const int k0 = kk * 64;
  #pragma unroll 8
  for (int k = k0; k < k0 + 64; ++k)
    acc = fmaf(ws[WS_CMM + k], Wcp[(size_t)k * D_ + d], acc);
  red[kk][d] = acc;
  __syncthreads();
  if (t < 64) {
    float a = bcp[t];
    #pragma unroll
    for (int i = 0; i < 16; ++i) a += red[i][t];
    ws[WS_PCMEAN + t] = a;
  }
}

template <int NR>
__device__ __forceinline__ void logits_kloop(const float* __restrict__ q, int row0,
                                             const float* __restrict__ W, int s,
                                             float* acc) {
  #pragma unroll 1
  for (int k = 0; k < H_; k += 4) {
    const float w0 = W[(size_t)(k + 0) * S_ + s];
    const float w1 = W[(size_t)(k + 1) * S_ + s];
    const float w2 = W[(size_t)(k + 2) * S_ + s];
    const float w3 = W[(size_t)(k + 3) * S_ + s];
    #pragma unroll
    for (int r = 0; r < NR; ++r) {
      const float4 qv = *reinterpret_cast<const float4*>(&q[(size_t)(row0 + r) * H_ + k]);
      float a = acc[r];
      a = fmaf(qv.x, w0, a);
      a = fmaf(qv.y, w1, a);
      a = fmaf(qv.z, w2, a);
      a = fmaf(qv.w, w3, a);
      acc[r] = a;
    }
  }
}

__global__ __launch_bounds__(512, 2) void k_read(
    const float* __restrict__ q, const float* __restrict__ cl,
    const float* __restrict__ Wr, const float* __restrict__ br,
    const float* __restrict__ strength, const float* __restrict__ mem,
    float* __restrict__ ws) {
  __shared__ float plds[BT * 512];
  const int t = threadIdx.x;
  const int r0 = blockIdx.x * BT;
  const int squar = blockIdx.y;
  const int d = t & 63, wv = t >> 6;

  float zacc[BT], tacc[BT];
  #pragma unroll
  for (int r = 0; r < BT; ++r) { zacc[r] = 0.f; tacc[r] = 0.f; }
  float vacc[4] = {0.f, 0.f, 0.f, 0.f};

  for (int tile = 0; tile < 16; ++tile) {
    const int sg0 = squar * 8192 + tile * 512;
    const int s = sg0 + t;
    float acc[BT];
    const float wlast = Wr[(size_t)H_ * S_ + s];
    const float bias = br[s];
    #pragma unroll
    for (int r = 0; r < BT; ++r) acc[r] = fmaf(cl[r0 + r], wlast, bias);
    logits_kloop<BT>(q, r0, Wr, s, acc);

    const float stg = strength[s];
    #pragma unroll
    for (int r = 0; r < BT; ++r) {
      const float e = __expf(acc[r]);
      zacc[r] += e;
      const float p = e * stg;
      tacc[r] += p;
      plds[r * 512 + t] = p;
    }
    __syncthreads();
    #pragma unroll 1
    for (int sl = 0; sl < 512; sl += 4) {
      const float m0 = mem[(size_t)(sg0 + sl + 0) * D_ + d];
      const float m1 = mem[(size_t)(sg0 + sl + 1) * D_ + d];
      const float m2 = mem[(size_t)(sg0 + sl + 2) * D_ + d];
      const float m3 = mem[(size_t)(sg0 + sl + 3) * D_ + d];
      #pragma unroll
      for (int j = 0; j < 4; ++j) {
        const float4 pv = *reinterpret_cast<const float4*>(&plds[(wv + 8 * j) * 512 + sl]);
        float v = vacc[j];
        v = fmaf(pv.x, m0, v);
        v = fmaf(pv.y, m1, v);
        v = fmaf(pv.z, m2, v);
        v = fmaf(pv.w, m3, v);
        vacc[j] = v;
      }
    }
    __syncthreads();
  }

  float* red0 = plds;
  float* red1 = plds + 8 * BT;
  #pragma unroll
  for (int r = 0; r < BT; ++r) {
    float z = zacc[r], tt = tacc[r];
    #pragma unroll
    for (int off = 32; off > 0; off >>= 1) {
      z += __shfl_down(z, off);
      tt += __shfl_down(tt, off);
    }
    if ((t & 63) == 0) { red0[wv * BT + r] = z; red1[wv * BT + r] = tt; }
  }
  __syncthreads();
  if (t < BT) {
    float z = 0.f, tt = 0.f;
    #pragma unroll
    for (int wq = 0; wq < 8; ++wq) { z += red0[wq * BT + t]; tt += red1[wq * BT + t]; }
    atomicAdd(&ws[WS_ZR + r0 + t], z);
    atomicAdd(&ws[WS_TR + r0 + t], tt);
  }
  #pragma unroll
  for (int j = 0; j < 4; ++j)
    atomicAdd(&ws[WS_VR + (size_t)(r0 + wv + 8 * j) * D_ + d], vacc[j]);
}

__global__ __launch_bounds__(512, 2) void k_write_pass1(
    const float* __restrict__ q, const float* __restrict__ cl,
    const float* __restrict__ Ww, const float* __restrict__ bw,
    float* __restrict__ ws, __hip_bfloat16* __restrict__ ebuf, const int store_e) {
  __shared__ float red[8 * BT];
  const int t = threadIdx.x;
  const int r0 = blockIdx.x * BT;
  const int squar = blockIdx.y;
  const int wv = t >> 6;

  float zacc[BT];
  #pragma unroll
  for (int r = 0; r < BT; ++r) zacc[r] = 0.f;

  for (int tile = 0; tile < 16; ++tile) {
    const int s = squar * 8192 + tile * 512 + t;
    float acc[BT];
    const float wlast = Ww[(size_t)H_ * S_ + s];
    const float bias = bw[s];
    #pragma unroll
    for (int r = 0; r < BT; ++r) acc[r] = fmaf(cl[r0 + r], wlast, bias);
    logits_kloop<BT>(q, r0, Ww, s, acc);
    #pragma unroll
    for (int r = 0; r < BT; ++r) {
      const float e = __expf(acc[r]);
      zacc[r] += e;
      if (store_e) ebuf[(size_t)(r0 + r) * S_ + s] = __float2bfloat16(e);
    }
  }
  #pragma unroll
  for (int r = 0; r < BT; ++r) {
    float z = zacc[r];
    #pragma unroll
    for (int off = 32; off > 0; off >>= 1) z += __shfl_down(z, off);
    if ((t & 63) == 0) red[wv * BT + r] = z;
  }
  __syncthreads();
  if (t < BT) {
    float z = 0.f;
    #pragma unroll
    for (int wq = 0; wq < 8; ++wq) z += red[wq * BT + t];
    atomicAdd(&ws[WS_ZW + r0 + t], z);
  }
}

__global__ void k_rc(const float* __restrict__ ws, float* __restrict__ out) {
  const int idx = blockIdx.x * 256 + threadIdx.x;
  const int b = idx >> 6;
  const float z = ws[WS_ZR + b], tt = ws[WS_TR + b];
  out[idx] = ws[WS_VR + idx] / (tt + 1e-6f * z);
}

__global__ void k_cboost(const float* __restrict__ rc, const float* __restrict__ Wce,
                         const float* __restrict__ bce, float* __restrict__ out) {
  const int idx = blockIdx.x * 256 + threadIdx.x;
  const int b = idx >> 10, h = idx & 1023;
  const float* __restrict__ rcb = &rc[b * 64];
  float acc = bce[h];
  #pragma unroll
  for (int dd = 0; dd < 64; dd += 4) {
    const float4 r4 = *reinterpret_cast<const float4*>(&rcb[dd]);
    acc = fmaf(r4.x, Wce[(size_t)(dd + 0) * H_ + h], acc);
    acc = fmaf(r4.y, Wce[(size_t)(dd + 1) * H_ + h], acc);
    acc = fmaf(r4.z, Wce[(size_t)(dd + 2) * H_ + h], acc);
    acc = fmaf(r4.w, Wce[(size_t)(dd + 3) * H_ + h], acc);
  }
  out[idx] = acc;
}

__global__ void k_wwm_store(const __hip_bfloat16* __restrict__ ebuf,
                            float* __restrict__ ws) {
  const int t = threadIdx.x;
  const int s0 = blockIdx.x * 2048 + t * 8;
  const int b0 = blockIdx.y * 128;
  const u16* __restrict__ eb = (const u16*)ebuf;
  float ww[8];
  #pragma unroll
  for (int j = 0; j < 8; ++j) ww[j] = 0.f;
  #pragma unroll 1
  for (int b = 0; b < 128; ++b) {
    const float inv = 1.0f / ws[WS_ZW + b0 + b];
    const ushort8v ev = *reinterpret_cast<const ushort8v*>(&eb[(size_t)(b0 + b) * S_ + s0]);
    #pragma unroll
    for (int j = 0; j < 8; ++j) {
      const float e = __uint_as_float(((unsigned)ev[j]) << 16);
      ww[j] = fmaf(e, inv, ww[j]);
    }
  }
  #pragma unroll
  for (int j = 0; j < 8; ++j) atomicAdd(&ws[WS_WWM + s0 + j], ww[j]);
}

__global__ __launch_bounds__(512, 2) void k_wwm_recompute(
    const float* __restrict__ q, const float* __restrict__ cl,
    const float* __restrict__ Ww, const float* __restrict__ bw,
    float* __restrict__ ws) {
  const int t = threadIdx.x;
  const int s = blockIdx.x * 512 + t;
  const int b0 = blockIdx.y * 256;
  const float wlast = Ww[(size_t)H_ * S_ + s];
  const float bias = bw[s];
  float wwacc = 0.f;
  for (int g = 0; g < 8; ++g) {
    const int rb = b0 + g * 32;
    float acc[BT];
    #pragma unroll
    for (int r = 0; r < BT; ++r) acc[r] = fmaf(cl[rb + r], wlast, bias);
    logits_kloop<BT>(q, rb, Ww, s, acc);
    #pragma unroll
    for (int r = 0; r < BT; ++r) wwacc += __expf(acc[r]) / ws[WS_ZW + rb + r];
  }
  atomicAdd(&ws[WS_WWM + s], wwacc);
}

// ================= launcher =================

extern "C" void kernel_launch(void* const* d_in, const int* in_sizes, int n_in,
                              void* d_out, int out_size, void* d_ws, size_t ws_size,
                              hipStream_t stream) {
  const float* query    = (const float*)d_in[0];
  const float* cl       = (const float*)d_in[1];
  const float* content  = (const float*)d_in[2];
  const float* memory   = (const float*)d_in[3];
  const float* age      = (const float*)d_in[4];
  const float* strength = (const float*)d_in[5];
  const float* W_read   = (const float*)d_in[6];
  const float* b_read   = (const float*)d_in[7];
  const float* W_write  = (const float*)d_in[8];
  const float* b_write  = (const float*)d_in[9];
  const float* W_cp     = (const float*)d_in[10];
  const float* b_cp     = (const float*)d_in[11];
  const float* W_ce     = (const float*)d_in[12];
  const float* b_ce     = (const float*)d_in[13];

  float* out = (float*)d_out;
  float* ws = (float*)d_ws;
  float* out_rc  = out;
  float* out_cb  = out + B_ * D_;
  float* out_mem = out_cb + (size_t)B_ * H_;
  float* out_age = out_mem + (size_t)S_ * D_;
  float* out_str = out_age + S_;

  // fast-path workspace layout (float offsets); vp (fp32) aliases pf8 region
  const size_t QB_F    = WS_END;
  const size_t MEMT_F  = QB_F + (size_t)B_ * KQS / 2;
  const size_t WBTR_F  = MEMT_F + (size_t)D_ * S_ / 2;
  const size_t WBTW_F  = WBTR_F + (size_t)S_ * KQS / 2;
  const size_t PBUF_F  = WBTW_F + (size_t)S_ * KQS / 2;
  const size_t FAST_END_F = PBUF_F + (size_t)128 * B_ * 64;   // ~53.7M floats

  hipMemsetAsync(ws, 0, (size_t)WS_END * sizeof(float), stream);

  if (ws_size >= FAST_END_F * sizeof(float)) {
    u16* qb   = (u16*)(ws + QB_F);
    u16* mT   = (u16*)(ws + MEMT_F);
    u16* wbtR = (u16*)(ws + WBTR_F);
    u16* wbtW = (u16*)(ws + WBTW_F);
    float* vp = (float*)(ws + PBUF_F);     // gemm<0> V-partials (fp32)
    u8*  pf8  = (u8*)(ws + PBUF_F);        // gemm<1> fp8 e-buffer (aliased, sequential)

    k_pre<<<160 + B_ + 512 + 2 * 8192, 256, 0, stream>>>(
        query, cl, content, memory, W_read, W_write, qb, mT, wbtR, wbtW, ws);
    k_gemm<0><<<dim3(8, 128), 512, 0, stream>>>(qb, wbtR, W_read, b_read, cl,
                                                strength, mT, (void*)vp, ws);
    k_rc2cb<<<513, 256, 0, stream>>>(vp, W_cp, b_cp, W_ce, b_ce, ws, out_rc, out_cb);
    k_gemm<1><<<dim3(8, 128), 512, 0, stream>>>(qb, wbtW, W_write, b_write, cl,
                                                nullptr, mT, (void*)pf8, ws);
    k_wwm_f8<<<dim3(8, 16), 256, 0, stream>>>(pf8, ws);
    k_final<<<(S_ * D_) / 256, 256, 0, stream>>>(memory, age, strength, ws,
                                                 out_mem, out_age, out_str);
  } else {
    const size_t ebuf_bytes = (size_t)B_ * S_ * 2;
    const int store_e = (ws_size >= (size_t)WS_END * 4 + ebuf_bytes) ? 1 : 0;
    __hip_bfloat16* ebuf = (__hip_bfloat16*)(ws + WS_END);

    k_stats<<<dim3(5, 32), 256, 0, stream>>>(content, cl, ws);
    k_pcmean<<<1, 1024, 0, stream>>>(W_cp, b_cp, ws);
    k_read<<<dim3(B_ / BT, 4), 512, 0, stream>>>(query, cl, W_read, b_read, strength, memory, ws);
    k_write_pass1<<<dim3(B_ / BT, 4), 512, 0, stream>>>(query, cl, W_write, b_write, ws, ebuf, store_e);
    k_rc<<<(B_ * D_) / 256, 256, 0, stream>>>(ws, out_rc);
    k_cboost<<<(B_ * H_) / 256, 256, 0, stream>>>(out_rc, W_ce, b_ce, out_cb);
    if (store_e) {
      k_wwm_store<<<dim3(S_ / 2048, B_ / 128), 256, 0, stream>>>(ebuf, ws);
    } else {
      k_wwm_recompute<<<dim3(S_ / 512, 8), 512, 0, stream>>>(query, cl, W_write, b_write, ws);
    }
    k_final<<<(S_ * D_) / 256, 256, 0, stream>>>(memory, age, strength, ws,
                                                 out_mem, out_age, out_str);
  }
}

// Round 10
// 673.368 us; speedup vs baseline: 1.1303x; 1.0758x over previous
//
#include <hip/hip_runtime.h>
#include <hip/hip_bf16.h>
#include <cstdint>
#include <cstddef>

#define B_ 2048
#define H_ 1024
#define S_ 32768
#define D_ 64
#define BT 32
#define KQ 1024   // GEMM K (query only); cl & bias folded into fp32 epilogue
#define NT 16     // K-tiles of 64

typedef unsigned char u8;
typedef unsigned short u16;
typedef __attribute__((ext_vector_type(8))) short bf16x8;
typedef __attribute__((ext_vector_type(8))) unsigned short ushort8v;
typedef __attribute__((ext_vector_type(4))) float f32x4;

// workspace layout (float offsets) -- shared by fast + fallback paths
#define WS_CMEAN      0
#define WS_PCMEAN     64
#define WS_CMM        128                    // content mean [H]
#define WS_ZR         (WS_CMM + H_)          // [B]
#define WS_TR         (WS_ZR + B_)           // [B]
#define WS_VR         (WS_TR + B_)           // [B*D] (fallback only)
#define WS_ZW         (WS_VR + B_*D_)        // [B]
#define WS_WWM        (WS_ZW + B_)           // [S]
#define WS_END        (WS_WWM + S_)          // 171136 floats

__device__ __forceinline__ u16 f2bf(float f) {
  unsigned u = __float_as_uint(f);
  unsigned r = (u + 0x7FFFu + ((u >> 16) & 1u)) >> 16;
  return (u16)r;
}

__device__ __forceinline__ float bf2f(u16 v) {
  return __uint_as_float(((unsigned)v) << 16);
}

// fp8 e4m3fn encode (f > 0, clamped to 448), RNE
__device__ __forceinline__ u8 f8enc(float f) {
  f = fminf(f, 448.f);
  unsigned u = __float_as_uint(f);
  int ex = (int)((u >> 23) & 255) - 127;
  unsigned r;
  if (ex >= -6) {
    unsigned m = u & 0x7FFFFF;
    unsigned rm = (m + 0x7FFFF + ((m >> 20) & 1)) >> 20;
    r = ((unsigned)(ex + 7) << 3) + rm;
  } else {
    r = (unsigned)fminf(7.f, f * 512.f + 0.5f);
  }
  return (u8)(r > 126 ? 126 : r);
}

__device__ __forceinline__ float f8dec(u8 b) {
  int ef = (b >> 3) & 15, m = b & 7;
  return ef ? __uint_as_float(((unsigned)(ef + 120) << 23) | ((unsigned)m << 20))
            : (float)m * 0.001953125f;
}

__device__ __forceinline__ void gload_lds16(const void* g, void* l) {
  __builtin_amdgcn_global_load_lds(
      (const __attribute__((address_space(1))) unsigned int*)g,
      (__attribute__((address_space(3))) unsigned int*)l, 16, 0, 0);
}

// ================= FAST PATH =================

// merged preprocessing: stats + cvt_q + cvt_memT + cvt_wt(read) + cvt_wt(write)
// grid sections (256 thr): [0,128) content-mean, [128,160) cl-mean,
// [160,2208) qb cast, [2208,2720) memT, [2720,10912) wbtR, [10912,19104) wbtW
__global__ void k_pre(const float* __restrict__ query, const float* __restrict__ cl,
                      const float* __restrict__ content, const float* __restrict__ mem,
                      const float* __restrict__ Wr, const float* __restrict__ Ww,
                      u16* __restrict__ qb, u16* __restrict__ mT,
                      u16* __restrict__ wbtR, u16* __restrict__ wbtW,
                      float* __restrict__ ws) {
  const int blk = blockIdx.x, t = threadIdx.x;
  if (blk < 128) {
    const int h = (blk & 3) * 256 + t;
    const int b0 = (blk >> 2) * 64;
    float acc = 0.f;
    #pragma unroll 8
    for (int b = 0; b < 64; ++b) acc += content[(size_t)(b0 + b) * H_ + h];
    atomicAdd(&ws[WS_CMM + h], acc * (1.0f / B_));
  } else if (blk < 160) {
    if (t < 64) {
      float acc = cl[(blk - 128) * 64 + t];
      #pragma unroll
      for (int off = 32; off > 0; off >>= 1) acc += __shfl_down(acc, off);
      if (t == 0) atomicAdd(&ws[WS_CMEAN], acc * (1.0f / B_));
    }
  } else if (blk < 160 + B_) {
    const int b = blk - 160;
    const float4 q4 = *reinterpret_cast<const float4*>(&query[(size_t)b * H_ + t * 4]);
    ushort4 o;
    o.x = f2bf(q4.x); o.y = f2bf(q4.y); o.z = f2bf(q4.z); o.w = f2bf(q4.w);
    *reinterpret_cast<ushort4*>(&qb[(size_t)b * KQ + t * 4]) = o;
  } else if (blk < 160 + B_ + 512) {
    __shared__ float tile[64][65];
    const int s0 = (blk - 160 - B_) * 64;
    const int c = t & 63, rbase = t >> 6;
    #pragma unroll
    for (int i = 0; i < 16; ++i) {
      const int r = rbase + i * 4;
      tile[r][c] = mem[(size_t)(s0 + r) * D_ + c];
    }
    __syncthreads();
    #pragma unroll
    for (int i = 0; i < 16; ++i) {
      const int d = rbase + i * 4;
      mT[(size_t)d * S_ + s0 + c] = f2bf(tile[c][d]);
    }
  } else {
    const int base = 160 + B_ + 512;
    const int isW = blk >= base + 8192;
    const int i = blk - base - (isW ? 8192 : 0);
    const float* __restrict__ W = isW ? Ww : Wr;
    u16* __restrict__ wbt = isW ? wbtW : wbtR;
    __shared__ float tile[64][65];
    const int s0 = (i & 511) * 64;
    const int k0 = (i >> 9) * 64;
    const int c = t & 63, rbase = t >> 6;
    #pragma unroll
    for (int j = 0; j < 16; ++j) {
      const int r = rbase + j * 4;
      tile[r][c] = W[(size_t)(k0 + r) * S_ + s0 + c];
    }
    __syncthreads();
    // vectorized store: each thread packs 8 consecutive k for one s-row,
    // 2 x 16B stores/thread (was 16 x 2B scalar stores)
    const int c8 = (t & 7) * 8;        // k offset within tile
    const int sr0 = t >> 3;            // 0..31
    #pragma unroll
    for (int j2 = 0; j2 < 2; ++j2) {
      const int srow = sr0 + 32 * j2;
      ushort8v o8;
      #pragma unroll
      for (int q = 0; q < 8; ++q) o8[q] = f2bf(tile[c8 + q][srow]);
      *reinterpret_cast<ushort8v*>(&wbt[(size_t)(s0 + srow) * KQ + k0 + c8]) = o8;
    }
  }
}

// LDS frag read: 16x16x32 A/B operand, rows rowbase+f*16+lr, 8-slot XOR swizzle
template <int NF>
__device__ __forceinline__ void rd_frags(const u16* __restrict__ lds, int rowbase,
                                         int lr, int lg, bf16x8 (&dst)[NF * 2]) {
  #pragma unroll
  for (int f = 0; f < NF; ++f) {
    const int rr = rowbase + f * 16 + lr;
    #pragma unroll
    for (int ks = 0; ks < 2; ++ks) {
      const int ch = (ks * 4 + lg) ^ (rr & 7);
      dst[f * 2 + ks] = *(const bf16x8*)&lds[rr * 64 + ch * 8];
    }
  }
}

template <int QR, int QC>
__device__ __forceinline__ void mfmaq(f32x4 (&acc)[8][4], const bf16x8 (&av)[8],
                                      const bf16x8 (&bv)[4]) {
  #pragma unroll
  for (int m16 = 0; m16 < 4; ++m16)
    #pragma unroll
    for (int n16 = 0; n16 < 2; ++n16)
      #pragma unroll
      for (int ks = 0; ks < 2; ++ks)
        acc[QR * 4 + m16][QC * 2 + n16] = __builtin_amdgcn_mfma_f32_16x16x32_bf16(
            av[m16 * 2 + ks], bv[n16 * 2 + ks], acc[QR * 4 + m16][QC * 2 + n16], 0, 0, 0);
}

// Fused bf16 MFMA GEMM, 8-phase/counted-vmcnt schedule, K=1024 (NT=16).
// logit = (qb @ wbt^T)[r][c] + cl[r]*W[1024][c] + bias[c] (fp32 epilogue add).
//  VARIANT 0 (read): p=e*strength -> LDS P-tile; Z/T row atomics; fused PV
//    (each wave owns a 32-row slice, contracts all 256 s vs memT);
//    fp32 V-partials -> vp[cblk][B][64] (pout).
//  VARIANT 1 (write): e -> LDS, coalesced fp8 e4m3 readout -> pout, Zw atomics.
// Block 512 thr (8 waves 2Mx4N), tile 256x256, BK=64, LDS 128KB.
template <int VARIANT>
__global__ __launch_bounds__(512, 2) void k_gemm(
    const u16* __restrict__ qb, const u16* __restrict__ wbt,
    const float* __restrict__ Wfull, const float* __restrict__ biasv,
    const float* __restrict__ cl, const float* __restrict__ strength,
    const u16* __restrict__ mT, void* __restrict__ pout, float* __restrict__ ws) {
  __shared__ __align__(16) u16 SMEM[4][256 * 64];  // [0..1]=A dbuf, [2..3]=B dbuf
  const int t = threadIdx.x;
  const int w = t >> 6, l = t & 63;
  const int wm = w >> 2, wn = w & 3;          // 2 x 4 waves
  const int lr = l & 15, lg = l >> 4;

  // bijective XCD-chunked remap: each XCD owns 16 contiguous col-blocks
  const int lin = blockIdx.x + 8 * blockIdx.y;   // gridDim = (8, 128)
  const int xcd = lin & 7, idx = lin >> 3;
  const size_t r0 = (size_t)(idx & 7) * 256;
  const int cblk = xcd * 16 + (idx >> 3);
  const size_t c0 = (size_t)cblk * 256;

  f32x4 acc[8][4];
  #pragma unroll
  for (int m = 0; m < 8; ++m)
    #pragma unroll
    for (int n = 0; n < 4; ++n) acc[m][n] = (f32x4)0.f;

  // stage K-tile kt2 into buffer pp: 8 gloads/thread, source pre-swizzled
  auto STAGE = [&](int kt2, int pp) {
    #pragma unroll
    for (int i = 0; i < 4; ++i) {
      const int q = i * 512 + t;
      const int r = q >> 3;
      const int sc = (q & 7) ^ (r & 7);
      gload_lds16(qb + (r0 + r) * KQ + (size_t)kt2 * 64 + sc * 8, &SMEM[pp][q * 8]);
    }
    #pragma unroll
    for (int i = 0; i < 4; ++i) {
      const int q = i * 512 + t;
      const int r = q >> 3;
      const int sc = (q & 7) ^ (r & 7);
      gload_lds16(wbt + (c0 + r) * KQ + (size_t)kt2 * 64 + sc * 8, &SMEM[2 + pp][q * 8]);
    }
  };

  // prologue: 2 K-tiles in flight
  STAGE(0, 0);
  STAGE(1, 1);
  asm volatile("s_waitcnt vmcnt(8)" ::: "memory");   // kt0 arrived, kt1 flying
  __builtin_amdgcn_sched_barrier(0);
  __builtin_amdgcn_s_barrier();

  for (int kt = 0; kt < NT; ++kt) {
    const int p = kt & 1;
    const u16* __restrict__ Ap = &SMEM[p][0];
    const u16* __restrict__ Bp = &SMEM[2 + p][0];
    bf16x8 a[8], b0[4], b1[4];
    // phase 1: read A(qr0)+B(qc0); MFMA quadrant (0,0)
    rd_frags<4>(Ap, wm * 128 + 0, lr, lg, a);
    rd_frags<2>(Bp, wn * 64 + 0, lr, lg, b0);
    __builtin_amdgcn_sched_barrier(0);
    __builtin_amdgcn_s_barrier();
    __builtin_amdgcn_s_setprio(1);
    mfmaq<0, 0>(acc, a, b0);
    __builtin_amdgcn_s_setprio(0);
    __builtin_amdgcn_s_barrier();
    // phase 2: read B(qc1); MFMA (0,1)
    rd_frags<2>(Bp, wn * 64 + 32, lr, lg, b1);
    __builtin_amdgcn_sched_barrier(0);
    __builtin_amdgcn_s_barrier();
    __builtin_amdgcn_s_setprio(1);
    mfmaq<0, 1>(acc, a, b1);
    __builtin_amdgcn_s_setprio(0);
    __builtin_amdgcn_s_barrier();
    // phase 3: read A(qr1); MFMA (1,1)
    rd_frags<4>(Ap, wm * 128 + 64, lr, lg, a);
    __builtin_amdgcn_sched_barrier(0);
    __builtin_amdgcn_s_barrier();
    __builtin_amdgcn_s_setprio(1);
    mfmaq<1, 1>(acc, a, b1);
    __builtin_amdgcn_s_setprio(0);
    __builtin_amdgcn_s_barrier();
    // phase 4: buf[p] LDS fully consumed -> stage kt+2 into it; MFMA (1,0) from regs
    if (kt + 2 < NT) STAGE(kt + 2, p);
    __builtin_amdgcn_s_barrier();
    __builtin_amdgcn_s_setprio(1);
    mfmaq<1, 0>(acc, a, b0);
    __builtin_amdgcn_s_setprio(0);
    if (kt + 2 < NT) {
      asm volatile("s_waitcnt vmcnt(8)" ::: "memory");   // kt+1 arrived, kt+2 flying
    } else if (kt + 1 < NT) {
      asm volatile("s_waitcnt vmcnt(0)" ::: "memory");   // tail drain
    }
    __builtin_amdgcn_sched_barrier(0);
    __builtin_amdgcn_s_barrier();
  }

  // ---------- epilogue ----------
  // C/D layout: col=lane&15, row=(lane>>4)*4+reg
  // fp32 rank-1 adjust: logit += cl[row]*W[1024][col] + bias[col]
  float wl4[4], bb4[4];
  #pragma unroll
  for (int n = 0; n < 4; ++n) {
    const size_t col = c0 + wn * 64 + n * 16 + lr;
    wl4[n] = Wfull[(size_t)H_ * S_ + col];
    bb4[n] = biasv[col];
  }
  #pragma unroll
  for (int m = 0; m < 8; ++m) {
    #pragma unroll
    for (int j = 0; j < 4; ++j) {
      const float clv = cl[r0 + wm * 128 + m * 16 + lg * 4 + j];
      #pragma unroll
      for (int n = 0; n < 4; ++n)
        acc[m][n][j] += fmaf(clv, wl4[n], bb4[n]);
    }
  }

  u16* __restrict__ Plds = &SMEM[0][0];   // [256][256] u16 = 128KB (all 4 buffers)

  if (VARIANT == 0) {
    // p = e*strength -> LDS P-tile; Z/T from registers
    float st4[4];
    #pragma unroll
    for (int n = 0; n < 4; ++n) st4[n] = strength[c0 + wn * 64 + n * 16 + lr];
    #pragma unroll
    for (int m = 0; m < 8; ++m) {
      #pragma unroll
      for (int j = 0; j < 4; ++j) {
        const int rloc = wm * 128 + m * 16 + lg * 4 + j;
        float ze = 0.f, zp = 0.f;
        #pragma unroll
        for (int n = 0; n < 4; ++n) {
          const float e = __expf(acc[m][n][j]);
          const float pq = e * st4[n];
          ze += e;
          zp += pq;
          const int col = wn * 64 + n * 16 + lr;
          const int ch = (col >> 3) ^ (rloc & 7);
          Plds[rloc * 256 + ch * 8 + (col & 7)] = f2bf(pq);
        }
        #pragma unroll
        for (int off = 1; off < 16; off <<= 1) {
          ze += __shfl_xor(ze, off);
          zp += __shfl_xor(zp, off);
        }
        if (lr == 0) {
          atomicAdd(&ws[WS_ZR + r0 + rloc], ze);
          atomicAdd(&ws[WS_TR + r0 + rloc], zp);
        }
      }
    }
    __syncthreads();
    // fused PV: wave w owns rows w*32..w*32+32, contracts over all 256 s
    float* __restrict__ vp = (float*)pout;
    f32x4 pv[2][4];
    #pragma unroll
    for (int f = 0; f < 2; ++f)
      #pragma unroll
      for (int n = 0; n < 4; ++n) pv[f][n] = (f32x4)0.f;
    #pragma unroll 2
    for (int ks = 0; ks < 8; ++ks) {
      bf16x8 pa[2], pb[4];
      #pragma unroll
      for (int f = 0; f < 2; ++f) {
        const int row = w * 32 + f * 16 + lr;
        const int ch = (ks * 4 + lg) ^ (row & 7);
        pa[f] = *(const bf16x8*)&Plds[row * 256 + ch * 8];
      }
      #pragma unroll
      for (int n = 0; n < 4; ++n)
        pb[n] = *(const bf16x8*)&mT[(size_t)(n * 16 + lr) * S_ + c0 + ks * 32 + lg * 8];
      #pragma unroll
      for (int f = 0; f < 2; ++f)
        #pragma unroll
        for (int n = 0; n < 4; ++n)
          pv[f][n] = __builtin_amdgcn_mfma_f32_16x16x32_bf16(pa[f], pb[n], pv[f][n], 0, 0, 0);
    }
    // store fp32 V-partials: vp[cblk][r0 + w*32 + row][d]
    #pragma unroll
    for (int f = 0; f < 2; ++f) {
      #pragma unroll
      for (int j = 0; j < 4; ++j) {
        const size_t R = (size_t)cblk * B_ + r0 + w * 32 + f * 16 + lg * 4 + j;
        #pragma unroll
        for (int n = 0; n < 4; ++n)
          vp[R * 64 + n * 16 + lr] = pv[f][n][j];
      }
    }
  } else {
    // write path: e -> LDS, coalesced fp8 readout + Zw
    #pragma unroll
    for (int m = 0; m < 8; ++m) {
      #pragma unroll
      for (int j = 0; j < 4; ++j) {
        const int rloc = wm * 128 + m * 16 + lg * 4 + j;
        #pragma unroll
        for (int n = 0; n < 4; ++n) {
          const int col = wn * 64 + n * 16 + lr;
          const int ch = (col >> 3) ^ (rloc & 7);
          Plds[rloc * 256 + ch * 8 + (col & 7)] = f2bf(__expf(acc[m][n][j]));
        }
      }
    }
    __syncthreads();
    u8* __restrict__ pout8 = (u8*)pout;
    #pragma unroll 2
    for (int it = 0; it < 8; ++it) {
      const int row = w * 32 + it * 4 + (l >> 4);
      const int c2 = (l & 15) * 2;        // two consecutive 8-col chunks
      const bf16x8 e0 = *(const bf16x8*)&Plds[row * 256 + ((c2 ^ (row & 7)) * 8)];
      const bf16x8 e1 = *(const bf16x8*)&Plds[row * 256 + (((c2 + 1) ^ (row & 7)) * 8)];
      float ze = 0.f;
      uint4 fb;
      unsigned wds[4] = {0, 0, 0, 0};
      #pragma unroll
      for (int q = 0; q < 8; ++q) {
        const float ea = bf2f((u16)e0[q]);
        const float eb = bf2f((u16)e1[q]);
        ze += ea + eb;
        wds[q >> 2] |= ((unsigned)f8enc(ea)) << ((q & 3) * 8);
        wds[2 + (q >> 2)] |= ((unsigned)f8enc(eb)) << ((q & 3) * 8);
      }
      fb.x = wds[0]; fb.y = wds[1]; fb.z = wds[2]; fb.w = wds[3];
      *(uint4*)&pout8[(r0 + row) * S_ + c0 + (size_t)(l & 15) * 16] = fb;
      #pragma unroll
      for (int off = 1; off < 16; off <<= 1) ze += __shfl_xor(ze, off);
      if ((l & 15) == 0) atomicAdd(&ws[WS_ZW + r0 + row], ze);
    }
  }
}

// merged: V-partial reduce + rc normalize + cboost; block 512 does pcmean
__global__ void k_rc2cb(const float* __restrict__ vp, const float* __restrict__ Wcp,
                        const float* __restrict__ bcp, const float* __restrict__ Wce,
                        const float* __restrict__ bce, float* __restrict__ ws,
                        float* __restrict__ out_rc, float* __restrict__ out_cb) {
  const int t = threadIdx.x;
  if (blockIdx.x == 512) {
    __shared__ float red[4][64];
    const int d = t & 63, kk = t >> 6;
    float acc = 0.f;
    #pragma unroll 8
    for (int k = kk * 256; k < kk * 256 + 256; ++k)
      acc = fmaf(ws[WS_CMM + k], Wcp[(size_t)k * D_ + d], acc);
    red[kk][d] = acc;
    __syncthreads();
    if (t < 64) {
      float a = bcp[t];
      #pragma unroll
      for (int i = 0; i < 4; ++i) a += red[i][t];
      ws[WS_PCMEAN + t] = a;
    }
    return;
  }
  __shared__ float rcs[4][64];
  const int idx = blockIdx.x * 256 + t;
  const int b = idx >> 6, d = idx & 63;
  float v = 0.f;
  #pragma unroll 4
  for (int c = 0; c < 128; ++c) v += vp[(size_t)c * B_ * 64 + idx];
  const float rcv = v / (ws[WS_TR + b] + 1e-6f * ws[WS_ZR + b]);
  out_rc[idx] = rcv;
  rcs[t >> 6][d] = rcv;
  __syncthreads();
  const int b0 = blockIdx.x * 4;
  #pragma unroll
  for (int oo = 0; oo < 4; ++oo) {
    const int h = oo * 256 + t;
    float a0 = bce[h], a1 = a0, a2 = a0, a3 = a0;
    #pragma unroll 8
    for (int dd = 0; dd < 64; ++dd) {
      const float wv = Wce[(size_t)dd * H_ + h];
      a0 = fmaf(rcs[0][dd], wv, a0);
      a1 = fmaf(rcs[1][dd], wv, a1);
      a2 = fmaf(rcs[2][dd], wv, a2);
      a3 = fmaf(rcs[3][dd], wv, a3);
    }
    out_cb[(size_t)(b0 + 0) * H_ + h] = a0;
    out_cb[(size_t)(b0 + 1) * H_ + h] = a1;
    out_cb[(size_t)(b0 + 2) * H_ + h] = a2;
    out_cb[(size_t)(b0 + 3) * H_ + h] = a3;
  }
}

// ================= shared small kernels =================

// ww_mean from fp8 e-buffer
__global__ void k_wwm_f8(const u8* __restrict__ ebuf, float* __restrict__ ws) {
  const int t = threadIdx.x;
  const int s0 = blockIdx.x * 4096 + t * 16;       // gridx = 8
  const int b0 = blockIdx.y * 128;                 // gridy = 16
  float ww[16];
  #pragma unroll
  for (int j = 0; j < 16; ++j) ww[j] = 0.f;
  #pragma unroll 1
  for (int b = 0; b < 128; ++b) {
    const float inv = 1.0f / ws[WS_ZW + b0 + b];
    const uint4 v = *reinterpret_cast<const uint4*>(&ebuf[(size_t)(b0 + b) * S_ + s0]);
    const unsigned vv[4] = {v.x, v.y, v.z, v.w};
    #pragma unroll
    for (int j = 0; j < 16; ++j) {
      const u8 byte = (u8)((vv[j >> 2] >> ((j & 3) * 8)) & 0xFF);
      ww[j] = fmaf(f8dec(byte), inv, ww[j]);
    }
  }
  #pragma unroll
  for (int j = 0; j < 16; ++j) atomicAdd(&ws[WS_WWM + s0 + j], ww[j]);
}

__global__ void k_final(const float* __restrict__ mem, const float* __restrict__ age,
                        const float* __restrict__ strength, const float* __restrict__ ws,
                        float* __restrict__ out_mem, float* __restrict__ out_age,
                        float* __restrict__ out_str) {
  const int idx = blockIdx.x * 256 + threadIdx.x;
  const int s = idx >> 6, dd = idx & 63;
  const float cm = ws[WS_CMEAN];
  const float w = ws[WS_WWM + s] * (2.0f * cm / B_);
  const bool mask = (w > 0.005f) && (cm >= 0.3f);
  float m = mem[idx];
  if (mask) {
    const float cons = 1.0f / (1.0f + __expf(-(age[s] * 0.1f + cm)));
    const float alpha = w * cons;
    m = (1.0f - alpha) * m + alpha * ws[WS_PCMEAN + dd];
  }
  out_mem[idx] = m;
  if (dd == 0) {
    out_age[s] = age[s] + (mask ? 1.0f : 0.0f);
    out_str[s] = mask ? fminf(fmaxf(strength[s] + w * 0.1f, 0.1f), 2.0f) : strength[s];
  }
}

// ================= FALLBACK PATH (fp32, round-1, known-passing) =================

__global__ void k_stats(const float* __restrict__ content,
                        const float* __restrict__ cl, float* __restrict__ ws) {
  const int gx = blockIdx.x, gy = blockIdx.y, t = threadIdx.x;
  if (gx < 4) {
    const int h = gx * 256 + t;
    const int b0 = gy * 64;
    float acc = 0.f;
    #pragma unroll 8
    for (int b = 0; b < 64; ++b) acc += content[(size_t)(b0 + b) * H_ + h];
    atomicAdd(&ws[WS_CMM + h], acc * (1.0f / B_));
  } else if (t < 64) {
    float acc = cl[gy * 64 + t];
    #pragma unroll
    for (int off = 32; off > 0; off >>= 1) acc += __shfl_down(acc, off);
    if (t == 0) atomicAdd(&ws[WS_CMEAN], acc * (1.0f / B_));
  }
}

__global__ void k_pcmean(const float* __restrict__ Wcp, const float* __restrict__ bcp,
                         float* __restrict__ ws) {
  __shared__ float red[16][64];
  const int t = threadIdx.x, d = t & 63, kk = t >> 6;
  float acc = 0.f;
  const int k0 = kk * 64;
  #pragma unroll 8
  for (int k = k0; k < k0 + 64; ++k)
    acc = fmaf(ws[WS_CMM + k], Wcp[(size_t)k * D_ + d], acc);
  red[kk][d] = acc;
  __syncthreads();
  if (t < 64) {
    float a = bcp[t];
    #pragma unroll
    for (int i = 0; i < 16; ++i) a += red[i][t];
    ws[WS_PCMEAN + t] = a;
  }
}

template <int NR>
__device__ __forceinline__ void logits_kloop(const float* __restrict__ q, int row0,
                                             const float* __restrict__ W, int s,
                                             float* acc) {
  #pragma unroll 1
  for (int k = 0; k < H_; k += 4) {
    const float w0 = W[(size_t)(k + 0) * S_ + s];
    const float w1 = W[(size_t)(k + 1) * S_ + s];
    const float w2 = W[(size_t)(k + 2) * S_ + s];
    const float w3 = W[(size_t)(k + 3) * S_ + s];
    #pragma unroll
    for (int r = 0; r < NR; ++r) {
      const float4 qv = *reinterpret_cast<const float4*>(&q[(size_t)(row0 + r) * H_ + k]);
      float a = acc[r];
      a = fmaf(qv.x, w0, a);
      a = fmaf(qv.y, w1, a);
      a = fmaf(qv.z, w2, a);
      a = fmaf(qv.w, w3, a);
      acc[r] = a;
    }
  }
}

__global__ __launch_bounds__(512, 2) void k_read(
    const float* __restrict__ q, const float* __restrict__ cl,
    const float* __restrict__ Wr, const float* __restrict__ br,
    const float* __restrict__ strength, const float* __restrict__ mem,
    float* __restrict__ ws) {
  __shared__ float plds[BT * 512];
  const int t = threadIdx.x;
  const int r0 = blockIdx.x * BT;
  const int squar = blockIdx.y;
  const int d = t & 63, wv = t >> 6;

  float zacc[BT], tacc[BT];
  #pragma unroll
  for (int r = 0; r < BT; ++r) { zacc[r] = 0.f; tacc[r] = 0.f; }
  float vacc[4] = {0.f, 0.f, 0.f, 0.f};

  for (int tile = 0; tile < 16; ++tile) {
    const int sg0 = squar * 8192 + tile * 512;
    const int s = sg0 + t;
    float acc[BT];
    const float wlast = Wr[(size_t)H_ * S_ + s];
    const float bias = br[s];
    #pragma unroll
    for (int r = 0; r < BT; ++r) acc[r] = fmaf(cl[r0 + r], wlast, bias);
    logits_kloop<BT>(q, r0, Wr, s, acc);

    const float stg = strength[s];
    #pragma unroll
    for (int r = 0; r < BT; ++r) {
      const float e = __expf(acc[r]);
      zacc[r] += e;
      const float p = e * stg;
      tacc[r] += p;
      plds[r * 512 + t] = p;
    }
    __syncthreads();
    #pragma unroll 1
    for (int sl = 0; sl < 512; sl += 4) {
      const float m0 = mem[(size_t)(sg0 + sl + 0) * D_ + d];
      const float m1 = mem[(size_t)(sg0 + sl + 1) * D_ + d];
      const float m2 = mem[(size_t)(sg0 + sl + 2) * D_ + d];
      const float m3 = mem[(size_t)(sg0 + sl + 3) * D_ + d];
      #pragma unroll
      for (int j = 0; j < 4; ++j) {
        const float4 pv = *reinterpret_cast<const float4*>(&plds[(wv + 8 * j) * 512 + sl]);
        float v = vacc[j];
        v = fmaf(pv.x, m0, v);
        v = fmaf(pv.y, m1, v);
        v = fmaf(pv.z, m2, v);
        v = fmaf(pv.w, m3, v);
        vacc[j] = v;
      }
    }
    __syncthreads();
  }

  float* red0 = plds;
  float* red1 = plds + 8 * BT;
  #pragma unroll
  for (int r = 0; r < BT; ++r) {
    float z = zacc[r], tt = tacc[r];
    #pragma unroll
    for (int off = 32; off > 0; off >>= 1) {
      z += __shfl_down(z, off);
      tt += __shfl_down(tt, off);
    }
    if ((t & 63) == 0) { red0[wv * BT + r] = z; red1[wv * BT + r] = tt; }
  }
  __syncthreads();
  if (t < BT) {
    float z = 0.f, tt = 0.f;
    #pragma unroll
    for (int wq = 0; wq < 8; ++wq) { z += red0[wq * BT + t]; tt += red1[wq * BT + t]; }
    atomicAdd(&ws[WS_ZR + r0 + t], z);
    atomicAdd(&ws[WS_TR + r0 + t], tt);
  }
  #pragma unroll
  for (int j = 0; j < 4; ++j)
    atomicAdd(&ws[WS_VR + (size_t)(r0 + wv + 8 * j) * D_ + d], vacc[j]);
}

__global__ __launch_bounds__(512, 2) void k_write_pass1(
    const float* __restrict__ q, const float* __restrict__ cl,
    const float* __restrict__ Ww, const float* __restrict__ bw,
    float* __restrict__ ws, __hip_bfloat16* __restrict__ ebuf, const int store_e) {
  __shared__ float red[8 * BT];
  const int t = threadIdx.x;
  const int r0 = blockIdx.x * BT;
  const int squar = blockIdx.y;
  const int wv = t >> 6;

  float zacc[BT];
  #pragma unroll
  for (int r = 0; r < BT; ++r) zacc[r] = 0.f;

  for (int tile = 0; tile < 16; ++tile) {
    const int s = squar * 8192 + tile * 512 + t;
    float acc[BT];
    const float wlast = Ww[(size_t)H_ * S_ + s];
    const float bias = bw[s];
    #pragma unroll
    for (int r = 0; r < BT; ++r) acc[r] = fmaf(cl[r0 + r], wlast, bias);
    logits_kloop<BT>(q, r0, Ww, s, acc);
    #pragma unroll
    for (int r = 0; r < BT; ++r) {
      const float e = __expf(acc[r]);
      zacc[r] += e;
      if (store_e) ebuf[(size_t)(r0 + r) * S_ + s] = __float2bfloat16(e);
    }
  }
  #pragma unroll
  for (int r = 0; r < BT; ++r) {
    float z = zacc[r];
    #pragma unroll
    for (int off = 32; off > 0; off >>= 1) z += __shfl_down(z, off);
    if ((t & 63) == 0) red[wv * BT + r] = z;
  }
  __syncthreads();
  if (t < BT) {
    float z = 0.f;
    #pragma unroll
    for (int wq = 0; wq < 8; ++wq) z += red[wq * BT + t];
    atomicAdd(&ws[WS_ZW + r0 + t], z);
  }
}

__global__ void k_rc(const float* __restrict__ ws, float* __restrict__ out) {
  const int idx = blockIdx.x * 256 + threadIdx.x;
  const int b = idx >> 6;
  const float z = ws[WS_ZR + b], tt = ws[WS_TR + b];
  out[idx] = ws[WS_VR + idx] / (tt + 1e-6f * z);
}

__global__ void k_cboost(const float* __restrict__ rc, const float* __restrict__ Wce,
                         const float* __restrict__ bce, float* __restrict__ out) {
  const int idx = blockIdx.x * 256 + threadIdx.x;
  const int b = idx >> 10, h = idx & 1023;
  const float* __restrict__ rcb = &rc[b * 64];
  float acc = bce[h];
  #pragma unroll
  for (int dd = 0; dd < 64; dd += 4) {
    const float4 r4 = *reinterpret_cast<const float4*>(&rcb[dd]);
    acc = fmaf(r4.x, Wce[(size_t)(dd + 0) * H_ + h], acc);
    acc = fmaf(r4.y, Wce[(size_t)(dd + 1) * H_ + h], acc);
    acc = fmaf(r4.z, Wce[(size_t)(dd + 2) * H_ + h], acc);
    acc = fmaf(r4.w, Wce[(size_t)(dd + 3) * H_ + h], acc);
  }
  out[idx] = acc;
}

__global__ void k_wwm_store(const __hip_bfloat16* __restrict__ ebuf,
                            float* __restrict__ ws) {
  const int t = threadIdx.x;
  const int s0 = blockIdx.x * 2048 + t * 8;
  const int b0 = blockIdx.y * 128;
  const u16* __restrict__ eb = (const u16*)ebuf;
  float ww[8];
  #pragma unroll
  for (int j = 0; j < 8; ++j) ww[j] = 0.f;
  #pragma unroll 1
  for (int b = 0; b < 128; ++b) {
    const float inv = 1.0f / ws[WS_ZW + b0 + b];
    const ushort8v ev = *reinterpret_cast<const ushort8v*>(&eb[(size_t)(b0 + b) * S_ + s0]);
    #pragma unroll
    for (int j = 0; j < 8; ++j) {
      const float e = __uint_as_float(((unsigned)ev[j]) << 16);
      ww[j] = fmaf(e, inv, ww[j]);
    }
  }
  #pragma unroll
  for (int j = 0; j < 8; ++j) atomicAdd(&ws[WS_WWM + s0 + j], ww[j]);
}

__global__ __launch_bounds__(512, 2) void k_wwm_recompute(
    const float* __restrict__ q, const float* __restrict__ cl,
    const float* __restrict__ Ww, const float* __restrict__ bw,
    float* __restrict__ ws) {
  const int t = threadIdx.x;
  const int s = blockIdx.x * 512 + t;
  const int b0 = blockIdx.y * 256;
  const float wlast = Ww[(size_t)H_ * S_ + s];
  const float bias = bw[s];
  float wwacc = 0.f;
  for (int g = 0; g < 8; ++g) {
    const int rb = b0 + g * 32;
    float acc[BT];
    #pragma unroll
    for (int r = 0; r < BT; ++r) acc[r] = fmaf(cl[rb + r], wlast, bias);
    logits_kloop<BT>(q, rb, Ww, s, acc);
    #pragma unroll
    for (int r = 0; r < BT; ++r) wwacc += __expf(acc[r]) / ws[WS_ZW + rb + r];
  }
  atomicAdd(&ws[WS_WWM + s], wwacc);
}

// ================= launcher =================

extern "C" void kernel_launch(void* const* d_in, const int* in_sizes, int n_in,
                              void* d_out, int out_size, void* d_ws, size_t ws_size,
                              hipStream_t stream) {
  const float* query    = (const float*)d_in[0];
  const float* cl       = (const float*)d_in[1];
  const float* content  = (const float*)d_in[2];
  const float* memory   = (const float*)d_in[3];
  const float* age      = (const float*)d_in[4];
  const float* strength = (const float*)d_in[5];
  const float* W_read   = (const float*)d_in[6];
  const float* b_read   = (const float*)d_in[7];
  const float* W_write  = (const float*)d_in[8];
  const float* b_write  = (const float*)d_in[9];
  const float* W_cp     = (const float*)d_in[10];
  const float* b_cp     = (const float*)d_in[11];
  const float* W_ce     = (const float*)d_in[12];
  const float* b_ce     = (const float*)d_in[13];

  float* out = (float*)d_out;
  float* ws = (float*)d_ws;
  float* out_rc  = out;
  float* out_cb  = out + B_ * D_;
  float* out_mem = out_cb + (size_t)B_ * H_;
  float* out_age = out_mem + (size_t)S_ * D_;
  float* out_str = out_age + S_;

  // fast-path workspace layout (float offsets); vp (fp32) aliases pf8 region
  const size_t QB_F    = WS_END;
  const size_t MEMT_F  = QB_F + (size_t)B_ * KQ / 2;
  const size_t WBTR_F  = MEMT_F + (size_t)D_ * S_ / 2;
  const size_t WBTW_F  = WBTR_F + (size_t)S_ * KQ / 2;
  const size_t PBUF_F  = WBTW_F + (size_t)S_ * KQ / 2;
  const size_t FAST_END_F = PBUF_F + (size_t)128 * B_ * 64;   // ~52.6M floats

  hipMemsetAsync(ws, 0, (size_t)WS_END * sizeof(float), stream);

  if (ws_size >= FAST_END_F * sizeof(float)) {
    u16* qb   = (u16*)(ws + QB_F);
    u16* mT   = (u16*)(ws + MEMT_F);
    u16* wbtR = (u16*)(ws + WBTR_F);
    u16* wbtW = (u16*)(ws + WBTW_F);
    float* vp = (float*)(ws + PBUF_F);     // gemm<0> V-partials (fp32)
    u8*  pf8  = (u8*)(ws + PBUF_F);        // gemm<1> fp8 e-buffer (aliased, sequential)

    k_pre<<<160 + B_ + 512 + 2 * 8192, 256, 0, stream>>>(
        query, cl, content, memory, W_read, W_write, qb, mT, wbtR, wbtW, ws);
    k_gemm<0><<<dim3(8, 128), 512, 0, stream>>>(qb, wbtR, W_read, b_read, cl,
                                                strength, mT, (void*)vp, ws);
    k_rc2cb<<<513, 256, 0, stream>>>(vp, W_cp, b_cp, W_ce, b_ce, ws, out_rc, out_cb);
    k_gemm<1><<<dim3(8, 128), 512, 0, stream>>>(qb, wbtW, W_write, b_write, cl,
                                                nullptr, mT, (void*)pf8, ws);
    k_wwm_f8<<<dim3(8, 16), 256, 0, stream>>>(pf8, ws);
    k_final<<<(S_ * D_) / 256, 256, 0, stream>>>(memory, age, strength, ws,
                                                 out_mem, out_age, out_str);
  } else {
    const size_t ebuf_bytes = (size_t)B_ * S_ * 2;
    const int store_e = (ws_size >= (size_t)WS_END * 4 + ebuf_bytes) ? 1 : 0;
    __hip_bfloat16* ebuf = (__hip_bfloat16*)(ws + WS_END);

    k_stats<<<dim3(5, 32), 256, 0, stream>>>(content, cl, ws);
    k_pcmean<<<1, 1024, 0, stream>>>(W_cp, b_cp, ws);
    k_read<<<dim3(B_ / BT, 4), 512, 0, stream>>>(query, cl, W_read, b_read, strength, memory, ws);
    k_write_pass1<<<dim3(B_ / BT, 4), 512, 0, stream>>>(query, cl, W_write, b_write, ws, ebuf, store_e);
    k_rc<<<(B_ * D_) / 256, 256, 0, stream>>>(ws, out_rc);
    k_cboost<<<(B_ * H_) / 256, 256, 0, stream>>>(out_rc, W_ce, b_ce, out_cb);
    if (store_e) {
      k_wwm_store<<<dim3(S_ / 2048, B_ / 128), 256, 0, stream>>>(ebuf, ws);
    } else {
      k_wwm_recompute<<<dim3(S_ / 512, 8), 512, 0, stream>>>(query, cl, W_write, b_write, ws);
    }
    k_final<<<(S_ * D_) / 256, 256, 0, stream>>>(memory, age, strength, ws,
                                                 out_mem, out_age, out_str);
  }
}

// Round 12
// 662.070 us; speedup vs baseline: 1.1496x; 1.0171x over previous
//
#include <hip/hip_runtime.h>
#include <hip/hip_bf16.h>
#include <cstdint>
#include <cstddef>

#define B_ 2048
#define H_ 1024
#define S_ 32768
#define D_ 64
#define BT 32
#define KQ 1024   // GEMM K (query only); cl & bias folded into fp32 epilogue
#define NT 16     // K-tiles of 64

typedef unsigned char u8;
typedef unsigned short u16;
typedef __attribute__((ext_vector_type(8))) short bf16x8;
typedef __attribute__((ext_vector_type(8))) unsigned short ushort8v;
typedef __attribute__((ext_vector_type(4))) float f32x4;

// workspace layout (float offsets) -- shared by fast + fallback paths
#define WS_CMEAN      0
#define WS_PCMEAN     64
#define WS_CMM        128                    // content mean [H]
#define WS_ZR         (WS_CMM + H_)          // [B]
#define WS_TR         (WS_ZR + B_)           // [B]
#define WS_VR         (WS_TR + B_)           // [B*D] (fallback only)
#define WS_ZW         (WS_VR + B_*D_)        // [B]
#define WS_WWM        (WS_ZW + B_)           // [S]
#define WS_END        (WS_WWM + S_)          // 171136 floats

__device__ __forceinline__ u16 f2bf(float f) {
  unsigned u = __float_as_uint(f);
  unsigned r = (u + 0x7FFFu + ((u >> 16) & 1u)) >> 16;
  return (u16)r;
}

__device__ __forceinline__ float bf2f(u16 v) {
  return __uint_as_float(((unsigned)v) << 16);
}

// fp8 e4m3fn encode (f > 0, clamped to 448), RNE
__device__ __forceinline__ u8 f8enc(float f) {
  f = fminf(f, 448.f);
  unsigned u = __float_as_uint(f);
  int ex = (int)((u >> 23) & 255) - 127;
  unsigned r;
  if (ex >= -6) {
    unsigned m = u & 0x7FFFFF;
    unsigned rm = (m + 0x7FFFF + ((m >> 20) & 1)) >> 20;
    r = ((unsigned)(ex + 7) << 3) + rm;
  } else {
    r = (unsigned)fminf(7.f, f * 512.f + 0.5f);
  }
  return (u8)(r > 126 ? 126 : r);
}

__device__ __forceinline__ float f8dec(u8 b) {
  int ef = (b >> 3) & 15, m = b & 7;
  return ef ? __uint_as_float(((unsigned)(ef + 120) << 23) | ((unsigned)m << 20))
            : (float)m * 0.001953125f;
}

__device__ __forceinline__ void gload_lds16(const void* g, void* l) {
  __builtin_amdgcn_global_load_lds(
      (const __attribute__((address_space(1))) unsigned int*)g,
      (__attribute__((address_space(3))) unsigned int*)l, 16, 0, 0);
}

// ================= FAST PATH =================

// merged preprocessing: stats + cvt_q + cvt_memT + cvt_wt(read) + cvt_wt(write)
__global__ void k_pre(const float* __restrict__ query, const float* __restrict__ cl,
                      const float* __restrict__ content, const float* __restrict__ mem,
                      const float* __restrict__ Wr, const float* __restrict__ Ww,
                      u16* __restrict__ qb, u16* __restrict__ mT,
                      u16* __restrict__ wbtR, u16* __restrict__ wbtW,
                      float* __restrict__ ws) {
  const int blk = blockIdx.x, t = threadIdx.x;
  if (blk < 128) {
    const int h = (blk & 3) * 256 + t;
    const int b0 = (blk >> 2) * 64;
    float acc = 0.f;
    #pragma unroll 8
    for (int b = 0; b < 64; ++b) acc += content[(size_t)(b0 + b) * H_ + h];
    atomicAdd(&ws[WS_CMM + h], acc * (1.0f / B_));
  } else if (blk < 160) {
    if (t < 64) {
      float acc = cl[(blk - 128) * 64 + t];
      #pragma unroll
      for (int off = 32; off > 0; off >>= 1) acc += __shfl_down(acc, off);
      if (t == 0) atomicAdd(&ws[WS_CMEAN], acc * (1.0f / B_));
    }
  } else if (blk < 160 + B_) {
    const int b = blk - 160;
    const float4 q4 = *reinterpret_cast<const float4*>(&query[(size_t)b * H_ + t * 4]);
    ushort4 o;
    o.x = f2bf(q4.x); o.y = f2bf(q4.y); o.z = f2bf(q4.z); o.w = f2bf(q4.w);
    *reinterpret_cast<ushort4*>(&qb[(size_t)b * KQ + t * 4]) = o;
  } else if (blk < 160 + B_ + 512) {
    __shared__ float tile[64][65];
    const int s0 = (blk - 160 - B_) * 64;
    const int c = t & 63, rbase = t >> 6;
    #pragma unroll
    for (int i = 0; i < 16; ++i) {
      const int r = rbase + i * 4;
      tile[r][c] = mem[(size_t)(s0 + r) * D_ + c];
    }
    __syncthreads();
    #pragma unroll
    for (int i = 0; i < 16; ++i) {
      const int d = rbase + i * 4;
      mT[(size_t)d * S_ + s0 + c] = f2bf(tile[c][d]);
    }
  } else {
    const int base = 160 + B_ + 512;
    const int isW = blk >= base + 8192;
    const int i = blk - base - (isW ? 8192 : 0);
    const float* __restrict__ W = isW ? Ww : Wr;
    u16* __restrict__ wbt = isW ? wbtW : wbtR;
    __shared__ float tile[64][65];
    const int s0 = (i & 511) * 64;
    const int k0 = (i >> 9) * 64;
    const int c = t & 63, rbase = t >> 6;
    #pragma unroll
    for (int j = 0; j < 16; ++j) {
      const int r = rbase + j * 4;
      tile[r][c] = W[(size_t)(k0 + r) * S_ + s0 + c];
    }
    __syncthreads();
    const int c8 = (t & 7) * 8;
    const int sr0 = t >> 3;
    #pragma unroll
    for (int j2 = 0; j2 < 2; ++j2) {
      const int srow = sr0 + 32 * j2;
      ushort8v o8;
      #pragma unroll
      for (int q = 0; q < 8; ++q) o8[q] = f2bf(tile[c8 + q][srow]);
      *reinterpret_cast<ushort8v*>(&wbt[(size_t)(s0 + srow) * KQ + k0 + c8]) = o8;
    }
  }
}

// LDS frag read: 16x16x32 A/B operand, rows rowbase+f*16+lr, 8-slot XOR swizzle
template <int NF>
__device__ __forceinline__ void rd_frags(const u16* __restrict__ lds, int rowbase,
                                         int lr, int lg, bf16x8 (&dst)[NF * 2]) {
  #pragma unroll
  for (int f = 0; f < NF; ++f) {
    const int rr = rowbase + f * 16 + lr;
    #pragma unroll
    for (int ks = 0; ks < 2; ++ks) {
      const int ch = (ks * 4 + lg) ^ (rr & 7);
      dst[f * 2 + ks] = *(const bf16x8*)&lds[rr * 64 + ch * 8];
    }
  }
}

template <int QR, int QC>
__device__ __forceinline__ void mfmaq(f32x4 (&acc)[8][4], const bf16x8 (&av)[8],
                                      const bf16x8 (&bv)[4]) {
  #pragma unroll
  for (int m16 = 0; m16 < 4; ++m16)
    #pragma unroll
    for (int n16 = 0; n16 < 2; ++n16)
      #pragma unroll
      for (int ks = 0; ks < 2; ++ks)
        acc[QR * 4 + m16][QC * 2 + n16] = __builtin_amdgcn_mfma_f32_16x16x32_bf16(
            av[m16 * 2 + ks], bv[n16 * 2 + ks], acc[QR * 4 + m16][QC * 2 + n16], 0, 0, 0);
}

// shared GEMM body (K-loop + epilogues); SMEM (128KB) is passed in so multiple
// inlined call sites share one per-kernel LDS allocation.
template <int IS_MERGED, int TVARIANT>
__device__ __forceinline__ void gemm_body(
    u16* __restrict__ SMEM, int variant, int bx, int by,
    const u16* __restrict__ qb, const u16* __restrict__ wbt,
    const float* __restrict__ Wfull, const float* __restrict__ biasv,
    const float* __restrict__ cl, const float* __restrict__ strength,
    const u16* __restrict__ mT, void* __restrict__ pout, float* __restrict__ ws) {
  const int t = threadIdx.x;
  const int w = t >> 6, l = t & 63;
  const int wm = w >> 2, wn = w & 3;          // 2 x 4 waves
  const int lr = l & 15, lg = l >> 4;

  // SMEM quadrants: [0..1]=A dbuf, [2..3]=B dbuf (each 256*64 u16)
  u16* __restrict__ SA0 = SMEM;
  u16* __restrict__ SA1 = SMEM + 256 * 64;
  u16* __restrict__ SB0 = SMEM + 2 * 256 * 64;
  u16* __restrict__ SB1 = SMEM + 3 * 256 * 64;

  // bijective XCD-chunked remap: each XCD owns 16 contiguous col-blocks
  const int lin = bx + 8 * by;                // by in [0,128)
  const int xcd = lin & 7, idx = lin >> 3;
  const size_t r0 = (size_t)(idx & 7) * 256;
  const int cblk = xcd * 16 + (idx >> 3);
  const size_t c0 = (size_t)cblk * 256;

  f32x4 acc[8][4];
  #pragma unroll
  for (int m = 0; m < 8; ++m)
    #pragma unroll
    for (int n = 0; n < 4; ++n) acc[m][n] = (f32x4)0.f;

  auto STAGE = [&](int kt2, int pp) {
    u16* __restrict__ SA = pp ? SA1 : SA0;
    u16* __restrict__ SB = pp ? SB1 : SB0;
    #pragma unroll
    for (int i = 0; i < 4; ++i) {
      const int q = i * 512 + t;
      const int r = q >> 3;
      const int sc = (q & 7) ^ (r & 7);
      gload_lds16(qb + (r0 + r) * KQ + (size_t)kt2 * 64 + sc * 8, &SA[q * 8]);
    }
    #pragma unroll
    for (int i = 0; i < 4; ++i) {
      const int q = i * 512 + t;
      const int r = q >> 3;
      const int sc = (q & 7) ^ (r & 7);
      gload_lds16(wbt + (c0 + r) * KQ + (size_t)kt2 * 64 + sc * 8, &SB[q * 8]);
    }
  };

  // prologue: 2 K-tiles in flight
  STAGE(0, 0);
  STAGE(1, 1);
  asm volatile("s_waitcnt vmcnt(8)" ::: "memory");
  __builtin_amdgcn_sched_barrier(0);
  __builtin_amdgcn_s_barrier();

  for (int kt = 0; kt < NT; ++kt) {
    const int p = kt & 1;
    const u16* __restrict__ Ap = p ? SA1 : SA0;
    const u16* __restrict__ Bp = p ? SB1 : SB0;
    bf16x8 a[8], b0[4], b1[4];
    // phase 1
    rd_frags<4>(Ap, wm * 128 + 0, lr, lg, a);
    rd_frags<2>(Bp, wn * 64 + 0, lr, lg, b0);
    __builtin_amdgcn_sched_barrier(0);
    __builtin_amdgcn_s_barrier();
    __builtin_amdgcn_s_setprio(1);
    mfmaq<0, 0>(acc, a, b0);
    __builtin_amdgcn_s_setprio(0);
    __builtin_amdgcn_s_barrier();
    // phase 2
    rd_frags<2>(Bp, wn * 64 + 32, lr, lg, b1);
    __builtin_amdgcn_sched_barrier(0);
    __builtin_amdgcn_s_barrier();
    __builtin_amdgcn_s_setprio(1);
    mfmaq<0, 1>(acc, a, b1);
    __builtin_amdgcn_s_setprio(0);
    __builtin_amdgcn_s_barrier();
    // phase 3
    rd_frags<4>(Ap, wm * 128 + 64, lr, lg, a);
    __builtin_amdgcn_sched_barrier(0);
    __builtin_amdgcn_s_barrier();
    __builtin_amdgcn_s_setprio(1);
    mfmaq<1, 1>(acc, a, b1);
    __builtin_amdgcn_s_setprio(0);
    __builtin_amdgcn_s_barrier();
    // phase 4
    if (kt + 2 < NT) STAGE(kt + 2, p);
    __builtin_amdgcn_s_barrier();
    __builtin_amdgcn_s_setprio(1);
    mfmaq<1, 0>(acc, a, b0);
    __builtin_amdgcn_s_setprio(0);
    if (kt + 2 < NT) {
      asm volatile("s_waitcnt vmcnt(8)" ::: "memory");
    } else if (kt + 1 < NT) {
      asm volatile("s_waitcnt vmcnt(0)" ::: "memory");
    }
    __builtin_amdgcn_sched_barrier(0);
    __builtin_amdgcn_s_barrier();
  }

  // ---------- epilogue ----------
  // fp32 rank-1 adjust: logit += cl[row]*W[1024][col] + bias[col]
  float wl4[4], bb4[4];
  #pragma unroll
  for (int n = 0; n < 4; ++n) {
    const size_t col = c0 + wn * 64 + n * 16 + lr;
    wl4[n] = Wfull[(size_t)H_ * S_ + col];
    bb4[n] = biasv[col];
  }
  #pragma unroll
  for (int m = 0; m < 8; ++m) {
    #pragma unroll
    for (int j = 0; j < 4; ++j) {
      const float clv = cl[r0 + wm * 128 + m * 16 + lg * 4 + j];
      #pragma unroll
      for (int n = 0; n < 4; ++n)
        acc[m][n][j] += fmaf(clv, wl4[n], bb4[n]);
    }
  }

  u16* __restrict__ Plds = SMEM;   // [256][256] u16 = 128KB

  const int v = IS_MERGED ? variant : TVARIANT;
  if (v == 0) {
    float st4[4];
    #pragma unroll
    for (int n = 0; n < 4; ++n) st4[n] = strength[c0 + wn * 64 + n * 16 + lr];
    #pragma unroll
    for (int m = 0; m < 8; ++m) {
      #pragma unroll
      for (int j = 0; j < 4; ++j) {
        const int rloc = wm * 128 + m * 16 + lg * 4 + j;
        float ze = 0.f, zp = 0.f;
        #pragma unroll
        for (int n = 0; n < 4; ++n) {
          const float e = __expf(acc[m][n][j]);
          const float pq = e * st4[n];
          ze += e;
          zp += pq;
          const int col = wn * 64 + n * 16 + lr;
          const int ch = (col >> 3) ^ (rloc & 7);
          Plds[rloc * 256 + ch * 8 + (col & 7)] = f2bf(pq);
        }
        #pragma unroll
        for (int off = 1; off < 16; off <<= 1) {
          ze += __shfl_xor(ze, off);
          zp += __shfl_xor(zp, off);
        }
        if (lr == 0) {
          atomicAdd(&ws[WS_ZR + r0 + rloc], ze);
          atomicAdd(&ws[WS_TR + r0 + rloc], zp);
        }
      }
    }
    __syncthreads();
    // fused PV: wave w owns rows w*32..w*32+32, contracts over all 256 s
    float* __restrict__ vp = (float*)pout;
    f32x4 pv[2][4];
    #pragma unroll
    for (int f = 0; f < 2; ++f)
      #pragma unroll
      for (int n = 0; n < 4; ++n) pv[f][n] = (f32x4)0.f;
    #pragma unroll 2
    for (int ks = 0; ks < 8; ++ks) {
      bf16x8 pa[2], pb[4];
      #pragma unroll
      for (int f = 0; f < 2; ++f) {
        const int row = w * 32 + f * 16 + lr;
        const int ch = (ks * 4 + lg) ^ (row & 7);
        pa[f] = *(const bf16x8*)&Plds[row * 256 + ch * 8];
      }
      #pragma unroll
      for (int n = 0; n < 4; ++n)
        pb[n] = *(const bf16x8*)&mT[(size_t)(n * 16 + lr) * S_ + c0 + ks * 32 + lg * 8];
      #pragma unroll
      for (int f = 0; f < 2; ++f)
        #pragma unroll
        for (int n = 0; n < 4; ++n)
          pv[f][n] = __builtin_amdgcn_mfma_f32_16x16x32_bf16(pa[f], pb[n], pv[f][n], 0, 0, 0);
    }
    #pragma unroll
    for (int f = 0; f < 2; ++f) {
      #pragma unroll
      for (int j = 0; j < 4; ++j) {
        const size_t R = (size_t)cblk * B_ + r0 + w * 32 + f * 16 + lg * 4 + j;
        #pragma unroll
        for (int n = 0; n < 4; ++n)
          vp[R * 64 + n * 16 + lr] = pv[f][n][j];
      }
    }
  } else {
    #pragma unroll
    for (int m = 0; m < 8; ++m) {
      #pragma unroll
      for (int j = 0; j < 4; ++j) {
        const int rloc = wm * 128 + m * 16 + lg * 4 + j;
        #pragma unroll
        for (int n = 0; n < 4; ++n) {
          const int col = wn * 64 + n * 16 + lr;
          const int ch = (col >> 3) ^ (rloc & 7);
          Plds[rloc * 256 + ch * 8 + (col & 7)] = f2bf(__expf(acc[m][n][j]));
        }
      }
    }
    __syncthreads();
    u8* __restrict__ pout8 = (u8*)pout;
    #pragma unroll 2
    for (int it = 0; it < 8; ++it) {
      const int row = w * 32 + it * 4 + (l >> 4);
      const int c2 = (l & 15) * 2;
      const bf16x8 e0 = *(const bf16x8*)&Plds[row * 256 + ((c2 ^ (row & 7)) * 8)];
      const bf16x8 e1 = *(const bf16x8*)&Plds[row * 256 + (((c2 + 1) ^ (row & 7)) * 8)];
      float ze = 0.f;
      uint4 fb;
      unsigned wds[4] = {0, 0, 0, 0};
      #pragma unroll
      for (int q = 0; q < 8; ++q) {
        const float ea = bf2f((u16)e0[q]);
        const float eb = bf2f((u16)e1[q]);
        ze += ea + eb;
        wds[q >> 2] |= ((unsigned)f8enc(ea)) << ((q & 3) * 8);
        wds[2 + (q >> 2)] |= ((unsigned)f8enc(eb)) << ((q & 3) * 8);
      }
      fb.x = wds[0]; fb.y = wds[1]; fb.z = wds[2]; fb.w = wds[3];
      *(uint4*)&pout8[(r0 + row) * S_ + c0 + (size_t)(l & 15) * 16] = fb;
      #pragma unroll
      for (int off = 1; off < 16; off <<= 1) ze += __shfl_xor(ze, off);
      if ((l & 15) == 0) atomicAdd(&ws[WS_ZW + r0 + row], ze);
    }
  }
}

// serial-path templated kernel (tier B, identical behavior to R10)
template <int VARIANT>
__global__ __launch_bounds__(512, 2) void k_gemm(
    const u16* __restrict__ qb, const u16* __restrict__ wbt,
    const float* __restrict__ Wfull, const float* __restrict__ biasv,
    const float* __restrict__ cl, const float* __restrict__ strength,
    const u16* __restrict__ mT, void* __restrict__ pout, float* __restrict__ ws) {
  __shared__ __align__(16) u16 SMEM[4 * 256 * 64];
  gemm_body<0, VARIANT>(SMEM, VARIANT, blockIdx.x, blockIdx.y, qb, wbt, Wfull,
                        biasv, cl, strength, mT, pout, ws);
}

// merged kernel (tier A): grid (8,256); by<128 = read-variant, by>=128 = write
__global__ __launch_bounds__(512, 2) void k_gemm2(
    const u16* __restrict__ qb, const u16* __restrict__ wbtR,
    const u16* __restrict__ wbtW,
    const float* __restrict__ Wr, const float* __restrict__ br,
    const float* __restrict__ Ww, const float* __restrict__ bw,
    const float* __restrict__ cl, const float* __restrict__ strength,
    const u16* __restrict__ mT, void* __restrict__ vp, void* __restrict__ pf8,
    float* __restrict__ ws) {
  __shared__ __align__(16) u16 SMEM[4 * 256 * 64];
  const int variant = (blockIdx.y >= 128) ? 1 : 0;
  const int by = blockIdx.y & 127;
  if (variant == 0)
    gemm_body<1, 0>(SMEM, 0, blockIdx.x, by, qb, wbtR, Wr, br, cl, strength,
                    mT, vp, ws);
  else
    gemm_body<1, 1>(SMEM, 1, blockIdx.x, by, qb, wbtW, Ww, bw, cl, strength,
                    mT, pf8, ws);
}

// merged: V-partial reduce + rc normalize + cboost; block 512 does pcmean
__global__ void k_rc2cb(const float* __restrict__ vp, const float* __restrict__ Wcp,
                        const float* __restrict__ bcp, const float* __restrict__ Wce,
                        const float* __restrict__ bce, float* __restrict__ ws,
                        float* __restrict__ out_rc, float* __restrict__ out_cb) {
  const int t = threadIdx.x;
  if (blockIdx.x == 512) {
    __shared__ float red[4][64];
    const int d = t & 63, kk = t >> 6;
    float acc = 0.f;
    #pragma unroll 8
    for (int k = kk * 256; k < kk * 256 + 256; ++k)
      acc = fmaf(ws[WS_CMM + k], Wcp[(size_t)k * D_ + d], acc);
    red[kk][d] = acc;
    __syncthreads();
    if (t < 64) {
      float a = bcp[t];
      #pragma unroll
      for (int i = 0; i < 4; ++i) a += red[i][t];
      ws[WS_PCMEAN + t] = a;
    }
    return;
  }
  __shared__ float rcs[4][64];
  const int idx = blockIdx.x * 256 + t;
  const int b = idx >> 6, d = idx & 63;
  float v = 0.f;
  #pragma unroll 4
  for (int c = 0; c < 128; ++c) v += vp[(size_t)c * B_ * 64 + idx];
  const float rcv = v / (ws[WS_TR + b] + 1e-6f * ws[WS_ZR + b]);
  out_rc[idx] = rcv;
  rcs[t >> 6][d] = rcv;
  __syncthreads();
  const int b0 = blockIdx.x * 4;
  #pragma unroll
  for (int oo = 0; oo < 4; ++oo) {
    const int h = oo * 256 + t;
    float a0 = bce[h], a1 = a0, a2 = a0, a3 = a0;
    #pragma unroll 8
    for (int dd = 0; dd < 64; ++dd) {
      const float wv = Wce[(size_t)dd * H_ + h];
      a0 = fmaf(rcs[0][dd], wv, a0);
      a1 = fmaf(rcs[1][dd], wv, a1);
      a2 = fmaf(rcs[2][dd], wv, a2);
      a3 = fmaf(rcs[3][dd], wv, a3);
    }
    out_cb[(size_t)(b0 + 0) * H_ + h] = a0;
    out_cb[(size_t)(b0 + 1) * H_ + h] = a1;
    out_cb[(size_t)(b0 + 2) * H_ + h] = a2;
    out_cb[(size_t)(b0 + 3) * H_ + h] = a3;
  }
}

// ================= shared small kernels =================

// ww_mean from fp8 e-buffer
__global__ void k_wwm_f8(const u8* __restrict__ ebuf, float* __restrict__ ws) {
  const int t = threadIdx.x;
  const int s0 = blockIdx.x * 4096 + t * 16;
  const int b0 = blockIdx.y * 128;
  float ww[16];
  #pragma unroll
  for (int j = 0; j < 16; ++j) ww[j] = 0.f;
  #pragma unroll 1
  for (int b = 0; b < 128; ++b) {
    const float inv = 1.0f / ws[WS_ZW + b0 + b];
    const uint4 v = *reinterpret_cast<const uint4*>(&ebuf[(size_t)(b0 + b) * S_ + s0]);
    const unsigned vv[4] = {v.x, v.y, v.z, v.w};
    #pragma unroll
    for (int j = 0; j < 16; ++j) {
      const u8 byte = (u8)((vv[j >> 2] >> ((j & 3) * 8)) & 0xFF);
      ww[j] = fmaf(f8dec(byte), inv, ww[j]);
    }
  }
  #pragma unroll
  for (int j = 0; j < 16; ++j) atomicAdd(&ws[WS_WWM + s0 + j], ww[j]);
}

__global__ void k_final(const float* __restrict__ mem, const float* __restrict__ age,
                        const float* __restrict__ strength, const float* __restrict__ ws,
                        float* __restrict__ out_mem, float* __restrict__ out_age,
                        float* __restrict__ out_str) {
  const int idx = blockIdx.x * 256 + threadIdx.x;
  const int s = idx >> 6, dd = idx & 63;
  const float cm = ws[WS_CMEAN];
  const float w = ws[WS_WWM + s] * (2.0f * cm / B_);
  const bool mask = (w > 0.005f) && (cm >= 0.3f);
  float m = mem[idx];
  if (mask) {
    const float cons = 1.0f / (1.0f + __expf(-(age[s] * 0.1f + cm)));
    const float alpha = w * cons;
    m = (1.0f - alpha) * m + alpha * ws[WS_PCMEAN + dd];
  }
  out_mem[idx] = m;
  if (dd == 0) {
    out_age[s] = age[s] + (mask ? 1.0f : 0.0f);
    out_str[s] = mask ? fminf(fmaxf(strength[s] + w * 0.1f, 0.1f), 2.0f) : strength[s];
  }
}

// ================= FALLBACK PATH (fp32, round-1, known-passing) =================

__global__ void k_stats(const float* __restrict__ content,
                        const float* __restrict__ cl, float* __restrict__ ws) {
  const int gx = blockIdx.x, gy = blockIdx.y, t = threadIdx.x;
  if (gx < 4) {
    const int h = gx * 256 + t;
    const int b0 = gy * 64;
    float acc = 0.f;
    #pragma unroll 8
    for (int b = 0; b < 64; ++b) acc += content[(size_t)(b0 + b) * H_ + h];
    atomicAdd(&ws[WS_CMM + h], acc * (1.0f / B_));
  } else if (t < 64) {
    float acc = cl[gy * 64 + t];
    #pragma unroll
    for (int off = 32; off > 0; off >>= 1) acc += __shfl_down(acc, off);
    if (t == 0) atomicAdd(&ws[WS_CMEAN], acc * (1.0f / B_));
  }
}

__global__ void k_pcmean(const float* __restrict__ Wcp, const float* __restrict__ bcp,
                         float* __restrict__ ws) {
  __shared__ float red[16][64];
  const int t = threadIdx.x, d = t & 63, kk = t >> 6;
  float acc = 0.f;
  const int k0 = kk * 64;
  #pragma unroll 8
  for (int k = k0; k < k0 + 64; ++k)
    acc = fmaf(ws[WS_CMM + k], Wcp[(size_t)k * D_ + d], acc);
  red[kk][d] = acc;
  __syncthreads();
  if (t < 64) {
    float a = bcp[t];
    #pragma unroll
    for (int i = 0; i < 16; ++i) a += red[i][t];
    ws[WS_PCMEAN + t] = a;
  }
}

template <int NR>
__device__ __forceinline__ void logits_kloop(const float* __restrict__ q, int row0,
                                             const float* __restrict__ W, int s,
                                             float* acc) {
  #pragma unroll 1
  for (int k = 0; k < H_; k += 4) {
    const float w0 = W[(size_t)(k + 0) * S_ + s];
    const float w1 = W[(size_t)(k + 1) * S_ + s];
    const float w2 = W[(size_t)(k + 2) * S_ + s];
    const float w3 = W[(size_t)(k + 3) * S_ + s];
    #pragma unroll
    for (int r = 0; r < NR; ++r) {
      const float4 qv = *reinterpret_cast<const float4*>(&q[(size_t)(row0 + r) * H_ + k]);
      float a = acc[r];
      a = fmaf(qv.x, w0, a);
      a = fmaf(qv.y, w1, a);
      a = fmaf(qv.z, w2, a);
      a = fmaf(qv.w, w3, a);
      acc[r] = a;
    }
  }
}

__global__ __launch_bounds__(512, 2) void k_read(
    const float* __restrict__ q, const float* __restrict__ cl,
    const float* __restrict__ Wr, const float* __restrict__ br,
    const float* __restrict__ strength, const float* __restrict__ mem,
    float* __restrict__ ws) {
  __shared__ float plds[BT * 512];
  const int t = threadIdx.x;
  const int r0 = blockIdx.x * BT;
  const int squar = blockIdx.y;
  const int d = t & 63, wv = t >> 6;

  float zacc[BT], tacc[BT];
  #pragma unroll
  for (int r = 0; r < BT; ++r) { zacc[r] = 0.f; tacc[r] = 0.f; }
  float vacc[4] = {0.f, 0.f, 0.f, 0.f};

  for (int tile = 0; tile < 16; ++tile) {
    const int sg0 = squar * 8192 + tile * 512;
    const int s = sg0 + t;
    float acc[BT];
    const float wlast = Wr[(size_t)H_ * S_ + s];
    const float bias = br[s];
    #pragma unroll
    for (int r = 0; r < BT; ++r) acc[r] = fmaf(cl[r0 + r], wlast, bias);
    logits_kloop<BT>(q, r0, Wr, s, acc);

    const float stg = strength[s];
    #pragma unroll
    for (int r = 0; r < BT; ++r) {
      const float e = __expf(acc[r]);
      zacc[r] += e;
      const float p = e * stg;
      tacc[r] += p;
      plds[r * 512 + t] = p;
    }
    __syncthreads();
    #pragma unroll 1
    for (int sl = 0; sl < 512; sl += 4) {
      const float m0 = mem[(size_t)(sg0 + sl + 0) * D_ + d];
      const float m1 = mem[(size_t)(sg0 + sl + 1) * D_ + d];
      const float m2 = mem[(size_t)(sg0 + sl + 2) * D_ + d];
      const float m3 = mem[(size_t)(sg0 + sl + 3) * D_ + d];
      #pragma unroll
      for (int j = 0; j < 4; ++j) {
        const float4 pv = *reinterpret_cast<const float4*>(&plds[(wv + 8 * j) * 512 + sl]);
        float v = vacc[j];
        v = fmaf(pv.x, m0, v);
        v = fmaf(pv.y, m1, v);
        v = fmaf(pv.z, m2, v);
        v = fmaf(pv.w, m3, v);
        vacc[j] = v;
      }
    }
    __syncthreads();
  }

  float* red0 = plds;
  float* red1 = plds + 8 * BT;
  #pragma unroll
  for (int r = 0; r < BT; ++r) {
    float z = zacc[r], tt = tacc[r];
    #pragma unroll
    for (int off = 32; off > 0; off >>= 1) {
      z += __shfl_down(z, off);
      tt += __shfl_down(tt, off);
    }
    if ((t & 63) == 0) { red0[wv * BT + r] = z; red1[wv * BT + r] = tt; }
  }
  __syncthreads();
  if (t < BT) {
    float z = 0.f, tt = 0.f;
    #pragma unroll
    for (int wq = 0; wq < 8; ++wq) { z += red0[wq * BT + t]; tt += red1[wq * BT + t]; }
    atomicAdd(&ws[WS_ZR + r0 + t], z);
    atomicAdd(&ws[WS_TR + r0 + t], tt);
  }
  #pragma unroll
  for (int j = 0; j < 4; ++j)
    atomicAdd(&ws[WS_VR + (size_t)(r0 + wv + 8 * j) * D_ + d], vacc[j]);
}

__global__ __launch_bounds__(512, 2) void k_write_pass1(
    const float* __restrict__ q, const float* __restrict__ cl,
    const float* __restrict__ Ww, const float* __restrict__ bw,
    float* __restrict__ ws, __hip_bfloat16* __restrict__ ebuf, const int store_e) {
  __shared__ float red[8 * BT];
  const int t = threadIdx.x;
  const int r0 = blockIdx.x * BT;
  const int squar = blockIdx.y;
  const int wv = t >> 6;

  float zacc[BT];
  #pragma unroll
  for (int r = 0; r < BT; ++r) zacc[r] = 0.f;

  for (int tile = 0; tile < 16; ++tile) {
    const int s = squar * 8192 + tile * 512 + t;
    float acc[BT];
    const float wlast = Ww[(size_t)H_ * S_ + s];
    const float bias = bw[s];
    #pragma unroll
    for (int r = 0; r < BT; ++r) acc[r] = fmaf(cl[r0 + r], wlast, bias);
    logits_kloop<BT>(q, r0, Ww, s, acc);
    #pragma unroll
    for (int r = 0; r < BT; ++r) {
      const float e = __expf(acc[r]);
      zacc[r] += e;
      if (store_e) ebuf[(size_t)(r0 + r) * S_ + s] = __float2bfloat16(e);
    }
  }
  #pragma unroll
  for (int r = 0; r < BT; ++r) {
    float z = zacc[r];
    #pragma unroll
    for (int off = 32; off > 0; off >>= 1) z += __shfl_down(z, off);
    if ((t & 63) == 0) red[wv * BT + r] = z;
  }
  __syncthreads();
  if (t < BT) {
    float z = 0.f;
    #pragma unroll
    for (int wq = 0; wq < 8; ++wq) z += red[wq * BT + t];
    atomicAdd(&ws[WS_ZW + r0 + t], z);
  }
}

__global__ void k_rc(const float* __restrict__ ws, float* __restrict__ out) {
  const int idx = blockIdx.x * 256 + threadIdx.x;
  const int b = idx >> 6;
  const float z = ws[WS_ZR + b], tt = ws[WS_TR + b];
  out[idx] = ws[WS_VR + idx] / (tt + 1e-6f * z);
}

__global__ void k_cboost(const float* __restrict__ rc, const float* __restrict__ Wce,
                         const float* __restrict__ bce, float* __restrict__ out) {
  const int idx = blockIdx.x * 256 + threadIdx.x;
  const int b = idx >> 10, h = idx & 1023;
  const float* __restrict__ rcb = &rc[b * 64];
  float acc = bce[h];
  #pragma unroll
  for (int dd = 0; dd < 64; dd += 4) {
    const float4 r4 = *reinterpret_cast<const float4*>(&rcb[dd]);
    acc = fmaf(r4.x, Wce[(size_t)(dd + 0) * H_ + h], acc);
    acc = fmaf(r4.y, Wce[(size_t)(dd + 1) * H_ + h], acc);
    acc = fmaf(r4.z, Wce[(size_t)(dd + 2) * H_ + h], acc);
    acc = fmaf(r4.w, Wce[(size_t)(dd + 3) * H_ + h], acc);
  }
  out[idx] = acc;
}

__global__ void k_wwm_store(const __hip_bfloat16* __restrict__ ebuf,
                            float* __restrict__ ws) {
  const int t = threadIdx.x;
  const int s0 = blockIdx.x * 2048 + t * 8;
  const int b0 = blockIdx.y * 128;
  const u16* __restrict__ eb = (const u16*)ebuf;
  float ww[8];
  #pragma unroll
  for (int j = 0; j < 8; ++j) ww[j] = 0.f;
  #pragma unroll 1
  for (int b = 0; b < 128; ++b) {
    const float inv = 1.0f / ws[WS_ZW + b0 + b];
    const ushort8v ev = *reinterpret_cast<const ushort8v*>(&eb[(size_t)(b0 + b) * S_ + s0]);
    #pragma unroll
    for (int j = 0; j < 8; ++j) {
      const float e = __uint_as_float(((unsigned)ev[j]) << 16);
      ww[j] = fmaf(e, inv, ww[j]);
    }
  }
  #pragma unroll
  for (int j = 0; j < 8; ++j) atomicAdd(&ws[WS_WWM + s0 + j], ww[j]);
}

__global__ __launch_bounds__(512, 2) void k_wwm_recompute(
    const float* __restrict__ q, const float* __restrict__ cl,
    const float* __restrict__ Ww, const float* __restrict__ bw,
    float* __restrict__ ws) {
  const int t = threadIdx.x;
  const int s = blockIdx.x * 512 + t;
  const int b0 = blockIdx.y * 256;
  const float wlast = Ww[(size_t)H_ * S_ + s];
  const float bias = bw[s];
  float wwacc = 0.f;
  for (int g = 0; g < 8; ++g) {
    const int rb = b0 + g * 32;
    float acc[BT];
    #pragma unroll
    for (int r = 0; r < BT; ++r) acc[r] = fmaf(cl[rb + r], wlast, bias);
    logits_kloop<BT>(q, rb, Ww, s, acc);
    #pragma unroll
    for (int r = 0; r < BT; ++r) wwacc += __expf(acc[r]) / ws[WS_ZW + rb + r];
  }
  atomicAdd(&ws[WS_WWM + s], wwacc);
}

// ================= launcher =================

extern "C" void kernel_launch(void* const* d_in, const int* in_sizes, int n_in,
                              void* d_out, int out_size, void* d_ws, size_t ws_size,
                              hipStream_t stream) {
  const float* query    = (const float*)d_in[0];
  const float* cl       = (const float*)d_in[1];
  const float* content  = (const float*)d_in[2];
  const float* memory   = (const float*)d_in[3];
  const float* age      = (const float*)d_in[4];
  const float* strength = (const float*)d_in[5];
  const float* W_read   = (const float*)d_in[6];
  const float* b_read   = (const float*)d_in[7];
  const float* W_write  = (const float*)d_in[8];
  const float* b_write  = (const float*)d_in[9];
  const float* W_cp     = (const float*)d_in[10];
  const float* b_cp     = (const float*)d_in[11];
  const float* W_ce     = (const float*)d_in[12];
  const float* b_ce     = (const float*)d_in[13];

  float* out = (float*)d_out;
  float* ws = (float*)d_ws;
  float* out_rc  = out;
  float* out_cb  = out + B_ * D_;
  float* out_mem = out_cb + (size_t)B_ * H_;
  float* out_age = out_mem + (size_t)S_ * D_;
  float* out_str = out_age + S_;

  // workspace layout (float offsets)
  const size_t QB_F    = WS_END;
  const size_t MEMT_F  = QB_F + (size_t)B_ * KQ / 2;
  const size_t WBTR_F  = MEMT_F + (size_t)D_ * S_ / 2;
  const size_t WBTW_F  = WBTR_F + (size_t)S_ * KQ / 2;
  const size_t PBUF_F  = WBTW_F + (size_t)S_ * KQ / 2;
  const size_t VPN_F   = PBUF_F;                              // vp (tier A & B)
  const size_t PF8N_F  = PBUF_F + (size_t)128 * B_ * 64;      // separate pf8 (tier A)
  const size_t FAST1_END_F = PBUF_F + (size_t)128 * B_ * 64;  // ~52.6M floats
  const size_t FAST2_END_F = PF8N_F + (size_t)B_ * S_ / 4;    // ~69.4M floats

  hipMemsetAsync(ws, 0, (size_t)WS_END * sizeof(float), stream);

  if (ws_size >= FAST2_END_F * sizeof(float)) {
    // Tier A: merged two-gemm dispatch (vp and pf8 disjoint)
    u16* qb   = (u16*)(ws + QB_F);
    u16* mT   = (u16*)(ws + MEMT_F);
    u16* wbtR = (u16*)(ws + WBTR_F);
    u16* wbtW = (u16*)(ws + WBTW_F);
    float* vp = (float*)(ws + VPN_F);
    u8*  pf8  = (u8*)(ws + PF8N_F);

    k_pre<<<160 + B_ + 512 + 2 * 8192, 256, 0, stream>>>(
        query, cl, content, memory, W_read, W_write, qb, mT, wbtR, wbtW, ws);
    k_gemm2<<<dim3(8, 256), 512, 0, stream>>>(qb, wbtR, wbtW, W_read, b_read,
                                              W_write, b_write, cl, strength,
                                              mT, (void*)vp, (void*)pf8, ws);
    k_rc2cb<<<513, 256, 0, stream>>>(vp, W_cp, b_cp, W_ce, b_ce, ws, out_rc, out_cb);
    k_wwm_f8<<<dim3(8, 16), 256, 0, stream>>>(pf8, ws);
    k_final<<<(S_ * D_) / 256, 256, 0, stream>>>(memory, age, strength, ws,
                                                 out_mem, out_age, out_str);
  } else if (ws_size >= FAST1_END_F * sizeof(float)) {
    // Tier B: R10 serial path (vp/pf8 aliased, sequential use)
    u16* qb   = (u16*)(ws + QB_F);
    u16* mT   = (u16*)(ws + MEMT_F);
    u16* wbtR = (u16*)(ws + WBTR_F);
    u16* wbtW = (u16*)(ws + WBTW_F);
    float* vp = (float*)(ws + PBUF_F);
    u8*  pf8  = (u8*)(ws + PBUF_F);

    k_pre<<<160 + B_ + 512 + 2 * 8192, 256, 0, stream>>>(
        query, cl, content, memory, W_read, W_write, qb, mT, wbtR, wbtW, ws);
    k_gemm<0><<<dim3(8, 128), 512, 0, stream>>>(qb, wbtR, W_read, b_read, cl,
                                                strength, mT, (void*)vp, ws);
    k_rc2cb<<<513, 256, 0, stream>>>(vp, W_cp, b_cp, W_ce, b_ce, ws, out_rc, out_cb);
    k_gemm<1><<<dim3(8, 128), 512, 0, stream>>>(qb, wbtW, W_write, b_write, cl,
                                                nullptr, mT, (void*)pf8, ws);
    k_wwm_f8<<<dim3(8, 16), 256, 0, stream>>>(pf8, ws);
    k_final<<<(S_ * D_) / 256, 256, 0, stream>>>(memory, age, strength, ws,
                                                 out_mem, out_age, out_str);
  } else {
    const size_t ebuf_bytes = (size_t)B_ * S_ * 2;
    const int store_e = (ws_size >= (size_t)WS_END * 4 + ebuf_bytes) ? 1 : 0;
    __hip_bfloat16* ebuf = (__hip_bfloat16*)(ws + WS_END);

    k_stats<<<dim3(5, 32), 256, 0, stream>>>(content, cl, ws);
    k_pcmean<<<1, 1024, 0, stream>>>(W_cp, b_cp, ws);
    k_read<<<dim3(B_ / BT, 4), 512, 0, stream>>>(query, cl, W_read, b_read, strength, memory, ws);
    k_write_pass1<<<dim3(B_ / BT, 4), 512, 0, stream>>>(query, cl, W_write, b_write, ws, ebuf, store_e);
    k_rc<<<(B_ * D_) / 256, 256, 0, stream>>>(ws, out_rc);
    k_cboost<<<(B_ * H_) / 256, 256, 0, stream>>>(out_rc, W_ce, b_ce, out_cb);
    if (store_e) {
      k_wwm_store<<<dim3(S_ / 2048, B_ / 128), 256, 0, stream>>>(ebuf, ws);
    } else {
      k_wwm_recompute<<<dim3(S_ / 512, 8), 512, 0, stream>>>(query, cl, W_write, b_write, ws);
    }
    k_final<<<(S_ * D_) / 256, 256, 0, stream>>>(memory, age, strength, ws,
                                                 out_mem, out_age, out_str);
  }
}